// Round 1
// baseline (475.653 us; speedup 1.0000x reference)
//
#include <hip/hip_runtime.h>
#include <hip/hip_bf16.h>
#include <math.h>

#define B_ 8
#define C_ 256
#define S_ 1024
#define N_ 512
#define KV_ 512
#define REL_ 64
#define NH_ 8
#define DH_ 64
#define KSEL_ 307

// ---------------- transpose h: (B,C,S) -> (B,S,C) ----------------
__global__ __launch_bounds__(256) void k_transpose_h(const float* __restrict__ h, float* __restrict__ hT) {
  __shared__ float tile[32][33];
  int b = blockIdx.z;
  int s0 = blockIdx.x * 32, c0 = blockIdx.y * 32;
  int x = threadIdx.x & 31, y0 = threadIdx.x >> 5;
  #pragma unroll
  for (int y = y0; y < 32; y += 8)
    tile[y][x] = h[((size_t)(b * C_ + c0 + y)) * S_ + s0 + x];
  __syncthreads();
  #pragma unroll
  for (int y = y0; y < 32; y += 8)
    hT[((size_t)(b * S_ + s0 + y)) * C_ + c0 + x] = tile[x][y];
}

// ---------------- generic tiled GEMM: C[m,n] = sum_k A[m,k] * W[n,k] + bias[n] ----------------
// A: M x Kd row-major, W: Nout x Kd row-major.
// trans_out==0: C[m*Nout+n]; trans_out==1: C[(b*C_+n)*S_ + s] with m = b*S_+s
__global__ __launch_bounds__(256) void k_gemm_bias(const float* __restrict__ A, const float* __restrict__ W,
                                                   const float* __restrict__ bias, float* __restrict__ Cout,
                                                   int M, int Nout, int Kd, int trans_out) {
  __shared__ float As[64][17];
  __shared__ float Bs[64][17];
  int tid = threadIdx.x;
  int tm = (tid >> 4) << 2;
  int tn = (tid & 15) << 2;
  int bm = blockIdx.x * 64;
  int bn = blockIdx.y * 64;
  float acc[4][4] = {};
  for (int k0 = 0; k0 < Kd; k0 += 16) {
    #pragma unroll
    for (int i = 0; i < 4; ++i) {
      int idx = tid + i * 256;
      int r = idx >> 4, k = idx & 15;
      As[r][k] = A[(size_t)(bm + r) * Kd + k0 + k];
      Bs[r][k] = W[(size_t)(bn + r) * Kd + k0 + k];
    }
    __syncthreads();
    #pragma unroll
    for (int k = 0; k < 16; ++k) {
      float a[4], bb[4];
      #pragma unroll
      for (int x = 0; x < 4; ++x) { a[x] = As[tm + x][k]; bb[x] = Bs[tn + x][k]; }
      #pragma unroll
      for (int x = 0; x < 4; ++x)
        #pragma unroll
        for (int y = 0; y < 4; ++y)
          acc[x][y] += a[x] * bb[y];
    }
    __syncthreads();
  }
  #pragma unroll
  for (int x = 0; x < 4; ++x) {
    int m = bm + tm + x;
    #pragma unroll
    for (int y = 0; y < 4; ++y) {
      int n = bn + tn + y;
      float v = acc[x][y] + bias[n];
      if (!trans_out) {
        Cout[(size_t)m * Nout + n] = v;
      } else {
        int b = m >> 10, s = m & 1023;
        Cout[((size_t)(b * C_ + n)) * S_ + s] = v;
      }
    }
  }
}

// ---------------- normalize rows of cp (4096 rows x 64), 1 wave per row ----------------
__global__ __launch_bounds__(256) void k_normalize(float* __restrict__ cp) {
  int row = blockIdx.x * 4 + (threadIdx.x >> 6);
  int d = threadIdx.x & 63;
  float x = cp[(size_t)row * 64 + d];
  float ss = x * x;
  #pragma unroll
  for (int off = 32; off; off >>= 1) ss += __shfl_xor(ss, off);
  float nrm = sqrtf(ss);
  cp[(size_t)row * 64 + d] = x / fmaxf(nrm, 1e-12f);
}

// ---------------- centrality[b,n] = x_n . (sum_m x_m) - x_n . x_n ----------------
__global__ __launch_bounds__(512) void k_centrality(const float* __restrict__ cp, float* __restrict__ cent) {
  int b = blockIdx.x;
  int tid = threadIdx.x; // 512
  __shared__ float part[8][64];
  __shared__ float vsum[64];
  int d = tid & 63, g = tid >> 6;
  float sacc = 0.f;
  for (int n = g * 64; n < g * 64 + 64; ++n)
    sacc += cp[((size_t)b * N_ + n) * 64 + d];
  part[g][d] = sacc;
  __syncthreads();
  if (tid < 64) {
    float v = 0.f;
    #pragma unroll
    for (int gg = 0; gg < 8; ++gg) v += part[gg][tid];
    vsum[tid] = v;
  }
  __syncthreads();
  const float* x = cp + ((size_t)b * N_ + tid) * 64;
  float dsum = 0.f, dself = 0.f;
  #pragma unroll
  for (int dd = 0; dd < 64; ++dd) {
    float xv = x[dd];
    dsum += xv * vsum[dd];
    dself += xv * xv;
  }
  cent[b * N_ + tid] = dsum - dself;
}

// ---------------- top-k select + mask + fallback ----------------
__global__ __launch_bounds__(512) void k_select(const float* __restrict__ cent, const int* __restrict__ mask,
                                                int* __restrict__ allowed) {
  int b = blockIdx.x, tid = threadIdx.x; // 512
  __shared__ float sc[512];
  __shared__ int anyflag;
  sc[tid] = cent[b * N_ + tid];
  if (tid == 0) anyflag = 0;
  __syncthreads();
  float v = sc[tid];
  int rank = 0;
  for (int j = 0; j < N_; ++j) {
    float u = sc[j];
    rank += (u > v) || (u == v && j < tid);
  }
  int sel = (rank < KSEL_) && (mask[b * N_ + tid] != 0);
  if (sel) anyflag = 1;  // benign race: all writers write 1
  __syncthreads();
  int outv = sel;
  if (anyflag == 0 && rank == 0) outv = 1;  // top-1 fallback (first argmax)
  allowed[b * N_ + tid] = outv;
}

// ---------------- flash attention over allowed keys; 1 query per thread ----------------
__global__ __launch_bounds__(256) void k_attn(const float* __restrict__ q, const float* __restrict__ Kp,
                                              const float* __restrict__ Vp, const int* __restrict__ allowed,
                                              float* __restrict__ attn_out) {
  __shared__ float Ks[64][64];
  __shared__ float Vs[64][64];
  __shared__ int alw[64];
  int bid = blockIdx.x;
  int qt = bid & 3, h = (bid >> 2) & 7, b = bid >> 5;
  int tid = threadIdx.x;
  int s = (qt << 8) + tid;
  const float4* qp4 = (const float4*)(q + (size_t)(b * S_ + s) * KV_ + h * DH_);
  float qv[64];
  float4* qv4 = (float4*)qv;
  #pragma unroll
  for (int i = 0; i < 16; ++i) qv4[i] = qp4[i];
  float mval = -1e30f, lval = 0.f;
  float acc[64];
  #pragma unroll
  for (int d = 0; d < 64; ++d) acc[d] = 0.f;

  for (int kc = 0; kc < N_; kc += 64) {
    #pragma unroll
    for (int i = 0; i < 16; ++i) {
      int idx = tid + i * 256;
      int kk = idx >> 6, d = idx & 63;
      Ks[kk][d] = Kp[(size_t)(b * N_ + kc + kk) * KV_ + h * DH_ + d];
      Vs[kk][d] = Vp[(size_t)(b * N_ + kc + kk) * KV_ + h * DH_ + d];
    }
    if (tid < 64) alw[tid] = allowed[b * N_ + kc + tid];
    __syncthreads();
    for (int kk = 0; kk < 64; ++kk) {
      if (!alw[kk]) continue;  // exact: masked keys have exp(-1e9 - max) == 0 in f32
      float sc = 0.f;
      const float4* kr = (const float4*)(&Ks[kk][0]);
      #pragma unroll
      for (int d4 = 0; d4 < 16; ++d4) {
        float4 kvv = kr[d4];
        sc += qv[d4 * 4 + 0] * kvv.x + qv[d4 * 4 + 1] * kvv.y + qv[d4 * 4 + 2] * kvv.z + qv[d4 * 4 + 3] * kvv.w;
      }
      sc *= 0.125f;
      float mn = fmaxf(mval, sc);
      float scale = __expf(mval - mn);
      float p = __expf(sc - mn);
      lval = lval * scale + p;
      const float4* vr = (const float4*)(&Vs[kk][0]);
      #pragma unroll
      for (int d4 = 0; d4 < 16; ++d4) {
        float4 vv = vr[d4];
        acc[d4 * 4 + 0] = acc[d4 * 4 + 0] * scale + p * vv.x;
        acc[d4 * 4 + 1] = acc[d4 * 4 + 1] * scale + p * vv.y;
        acc[d4 * 4 + 2] = acc[d4 * 4 + 2] * scale + p * vv.z;
        acc[d4 * 4 + 3] = acc[d4 * 4 + 3] * scale + p * vv.w;
      }
      mval = mn;
    }
    __syncthreads();
  }
  float inv = 1.0f / lval;
  float* optr = attn_out + (size_t)(b * S_ + s) * KV_ + h * DH_;
  float4* op4 = (float4*)optr;
  #pragma unroll
  for (int i = 0; i < 16; ++i) {
    float4 o;
    o.x = acc[i * 4 + 0] * inv;
    o.y = acc[i * 4 + 1] * inv;
    o.z = acc[i * 4 + 2] * inv;
    o.w = acc[i * 4 + 3] * inv;
    op4[i] = o;
  }
}

extern "C" void kernel_launch(void* const* d_in, const int* in_sizes, int n_in,
                              void* d_out, int out_size, void* d_ws, size_t ws_size,
                              hipStream_t stream) {
  const float* h         = (const float*)d_in[0];
  const float* cond      = (const float*)d_in[1];
  const int*   cond_mask = (const int*)d_in[2];
  const float* Wq = (const float*)d_in[3];
  const float* bq = (const float*)d_in[4];
  const float* Wk = (const float*)d_in[5];
  const float* bk = (const float*)d_in[6];
  const float* Wv = (const float*)d_in[7];
  const float* bv = (const float*)d_in[8];
  // d_in[9]=Wrq, d_in[10]=brq : unused branch (qg_proj) — output-independent
  const float* Wrk = (const float*)d_in[11];
  const float* brk = (const float*)d_in[12];
  const float* Wo  = (const float*)d_in[13];
  const float* bo  = (const float*)d_in[14];
  float* out = (float*)d_out;

  float* ws = (float*)d_ws;
  float* hT       = ws;                        // 2,097,152
  float* qbuf     = hT + (size_t)B_ * S_ * C_;         // 4,194,304
  float* Kp       = qbuf + (size_t)B_ * S_ * KV_;      // 2,097,152
  float* Vp       = Kp + (size_t)B_ * N_ * KV_;        // 2,097,152
  float* cp       = Vp + (size_t)B_ * N_ * KV_;        // 262,144
  float* cent     = cp + (size_t)B_ * N_ * REL_;       // 4,096
  float* attn_out = cent + (size_t)B_ * N_;            // 4,194,304
  int*   allowed  = (int*)(attn_out + (size_t)B_ * S_ * KV_);  // 4,096 ints

  // 1. transpose h -> (B,S,C)
  k_transpose_h<<<dim3(S_ / 32, C_ / 32, B_), 256, 0, stream>>>(h, hT);
  // 2. q projection: (8192 x 256) @ (512 x 256)^T
  k_gemm_bias<<<dim3((B_ * S_) / 64, KV_ / 64), 256, 0, stream>>>(hT, Wq, bq, qbuf, B_ * S_, KV_, C_, 0);
  // 3. K projection
  k_gemm_bias<<<dim3((B_ * N_) / 64, KV_ / 64), 256, 0, stream>>>(cond, Wk, bk, Kp, B_ * N_, KV_, KV_, 0);
  // 4. V projection
  k_gemm_bias<<<dim3((B_ * N_) / 64, KV_ / 64), 256, 0, stream>>>(cond, Wv, bv, Vp, B_ * N_, KV_, KV_, 0);
  // 5. rel projection (cond_proj before normalize)
  k_gemm_bias<<<dim3((B_ * N_) / 64, REL_ / 64), 256, 0, stream>>>(cond, Wrk, brk, cp, B_ * N_, REL_, KV_, 0);
  // 6. normalize rows
  k_normalize<<<(B_ * N_) / 4, 256, 0, stream>>>(cp);
  // 7. centrality
  k_centrality<<<B_, 512, 0, stream>>>(cp, cent);
  // 8. top-k + mask + fallback
  k_select<<<B_, 512, 0, stream>>>(cent, cond_mask, allowed);
  // 9. attention
  k_attn<<<B_ * NH_ * (S_ / 256), 256, 0, stream>>>(qbuf, Kp, Vp, allowed, attn_out);
  // 10. output projection with transposed store -> (B,C,H,W)
  k_gemm_bias<<<dim3((B_ * S_) / 64, C_ / 64), 256, 0, stream>>>(attn_out, Wo, bo, out, B_ * S_, C_, KV_, 1);
}

// Round 2
// 270.332 us; speedup vs baseline: 1.7595x; 1.7595x over previous
//
#include <hip/hip_runtime.h>
#include <math.h>

#define B_ 8
#define C_ 256
#define S_ 1024
#define N_ 512
#define KV_ 512
#define REL_ 64
#define NH_ 8
#define DH_ 64
#define KSEL_ 307

typedef __attribute__((ext_vector_type(8))) short bf16x8;
typedef __attribute__((ext_vector_type(4))) short short4v;
typedef __attribute__((ext_vector_type(4))) float f32x4;

__device__ __forceinline__ short f2bf(float f) {
  unsigned int u = __float_as_uint(f);
  u += 0x7fffu + ((u >> 16) & 1u);
  return (short)(u >> 16);
}

// ---------------- f32 -> bf16 convert (vector x4) ----------------
__global__ __launch_bounds__(256) void k_f32_to_bf16(const float* __restrict__ in, short* __restrict__ out, int n4) {
  int i = blockIdx.x * 256 + threadIdx.x;
  if (i >= n4) return;
  float4 v = ((const float4*)in)[i];
  short4v o = { f2bf(v.x), f2bf(v.y), f2bf(v.z), f2bf(v.w) };
  ((short4v*)out)[i] = o;
}

// ---------------- transpose h: (B,C,S) f32 -> (B,S,C) bf16 ----------------
__global__ __launch_bounds__(256) void k_transpose_h_bf16(const float* __restrict__ h, short* __restrict__ hT) {
  __shared__ float tile[32][33];
  int b = blockIdx.z;
  int s0 = blockIdx.x * 32, c0 = blockIdx.y * 32;
  int x = threadIdx.x & 31, y0 = threadIdx.x >> 5;
  #pragma unroll
  for (int y = y0; y < 32; y += 8)
    tile[y][x] = h[((size_t)(b * C_ + c0 + y)) * S_ + s0 + x];
  __syncthreads();
  #pragma unroll
  for (int y = y0; y < 32; y += 8)
    hT[((size_t)(b * S_ + s0 + y)) * C_ + c0 + x] = f2bf(tile[x][y]);
}

// ---------------- transpose out: (B,S,C) f32 -> (B,C,S) f32 ----------------
__global__ __launch_bounds__(256) void k_transpose_sc(const float* __restrict__ in, float* __restrict__ out) {
  __shared__ float tile[32][33];
  int b = blockIdx.z;
  int c0 = blockIdx.x * 32, s0 = blockIdx.y * 32;
  int x = threadIdx.x & 31, y0 = threadIdx.x >> 5;
  #pragma unroll
  for (int y = y0; y < 32; y += 8)
    tile[y][x] = in[((size_t)(b * S_ + s0 + y)) * C_ + c0 + x];
  __syncthreads();
  #pragma unroll
  for (int y = y0; y < 32; y += 8)
    out[((size_t)(b * C_ + c0 + y)) * S_ + s0 + x] = tile[x][y];
}

// ---------------- MFMA bf16 GEMM: C[m,n] = sum_k A[m,k]*W[n,k] + bias[n] ----------------
// A: M x Kd bf16 row-major, W: Nout x Kd bf16 row-major, C: f32 M x Nout.
// 128x128 tile, BK=64, 4 waves (2x2), each wave 64x64 = 4x4 fragments of 16x16x32.
#define BM 128
#define BN 128
#define BKG 64
__global__ __launch_bounds__(256) void k_mfma_gemm(const short* __restrict__ A, const short* __restrict__ W,
                                                   const float* __restrict__ bias, float* __restrict__ Cout,
                                                   int M, int Nout, int Kd) {
  __shared__ short As[BM][BKG];  // 16 KB
  __shared__ short Bs[BN][BKG];  // 16 KB
  int tid = threadIdx.x;
  int lane = tid & 63, wid = tid >> 6;
  int wr = wid >> 1, wc = wid & 1;
  size_t bm = (size_t)blockIdx.x * BM, bn = (size_t)blockIdx.y * BN;
  f32x4 acc[4][4] = {};
  int lrow = lane >> 3;          // 0..7
  int lcol = (lane & 7) * 8;     // 0,8,...,56 (bf16 elems)
  for (int k0 = 0; k0 < Kd; k0 += BKG) {
    // stage A and B tiles: per wave 4 instrs each, lane l -> ldsbase + l*16
    #pragma unroll
    for (int i = 0; i < 4; ++i) {
      int r0 = wid * 32 + i * 8;
      const short* gp = A + (bm + r0 + lrow) * Kd + k0 + lcol;
      __builtin_amdgcn_global_load_lds((const __attribute__((address_space(1))) void*)gp,
                                       (__attribute__((address_space(3))) void*)&As[r0][0], 16, 0, 0);
    }
    #pragma unroll
    for (int i = 0; i < 4; ++i) {
      int r0 = wid * 32 + i * 8;
      const short* gp = W + (bn + r0 + lrow) * Kd + k0 + lcol;
      __builtin_amdgcn_global_load_lds((const __attribute__((address_space(1))) void*)gp,
                                       (__attribute__((address_space(3))) void*)&Bs[r0][0], 16, 0, 0);
    }
    asm volatile("s_waitcnt vmcnt(0)" ::: "memory");
    __syncthreads();
    #pragma unroll
    for (int kk = 0; kk < BKG; kk += 32) {
      bf16x8 a[4], b[4];
      #pragma unroll
      for (int m = 0; m < 4; ++m)
        a[m] = *(const bf16x8*)&As[wr * 64 + m * 16 + (lane & 15)][kk + (lane >> 4) * 8];
      #pragma unroll
      for (int n = 0; n < 4; ++n)
        b[n] = *(const bf16x8*)&Bs[wc * 64 + n * 16 + (lane & 15)][kk + (lane >> 4) * 8];
      #pragma unroll
      for (int m = 0; m < 4; ++m)
        #pragma unroll
        for (int n = 0; n < 4; ++n)
          acc[m][n] = __builtin_amdgcn_mfma_f32_16x16x32_bf16(a[m], b[n], acc[m][n], 0, 0, 0);
    }
    __syncthreads();
  }
  // epilogue: D col = lane&15, row = (lane>>4)*4 + j  [HW-verified mapping]
  int c0 = lane & 15, r0q = lane >> 4;
  #pragma unroll
  for (int n = 0; n < 4; ++n) {
    size_t col = bn + wc * 64 + n * 16 + c0;
    float bv = bias[col];
    #pragma unroll
    for (int m = 0; m < 4; ++m) {
      #pragma unroll
      for (int j = 0; j < 4; ++j) {
        size_t row = bm + wr * 64 + m * 16 + r0q * 4 + j;
        Cout[row * Nout + col] = acc[m][n][j] + bv;
      }
    }
  }
}

// ---------------- f32 tiled GEMM (selector rel-proj only, kept exact) ----------------
__global__ __launch_bounds__(256) void k_gemm_bias(const float* __restrict__ A, const float* __restrict__ W,
                                                   const float* __restrict__ bias, float* __restrict__ Cout,
                                                   int M, int Nout, int Kd) {
  __shared__ float As[64][17];
  __shared__ float Bs[64][17];
  int tid = threadIdx.x;
  int tm = (tid >> 4) << 2;
  int tn = (tid & 15) << 2;
  int bm = blockIdx.x * 64;
  int bn = blockIdx.y * 64;
  float acc[4][4] = {};
  for (int k0 = 0; k0 < Kd; k0 += 16) {
    #pragma unroll
    for (int i = 0; i < 4; ++i) {
      int idx = tid + i * 256;
      int r = idx >> 4, k = idx & 15;
      As[r][k] = A[(size_t)(bm + r) * Kd + k0 + k];
      Bs[r][k] = W[(size_t)(bn + r) * Kd + k0 + k];
    }
    __syncthreads();
    #pragma unroll
    for (int k = 0; k < 16; ++k) {
      float a[4], bb[4];
      #pragma unroll
      for (int x = 0; x < 4; ++x) { a[x] = As[tm + x][k]; bb[x] = Bs[tn + x][k]; }
      #pragma unroll
      for (int x = 0; x < 4; ++x)
        #pragma unroll
        for (int y = 0; y < 4; ++y)
          acc[x][y] += a[x] * bb[y];
    }
    __syncthreads();
  }
  #pragma unroll
  for (int x = 0; x < 4; ++x) {
    int m = bm + tm + x;
    #pragma unroll
    for (int y = 0; y < 4; ++y) {
      int n = bn + tn + y;
      Cout[(size_t)m * Nout + n] = acc[x][y] + bias[n];
    }
  }
}

// ---------------- normalize rows of cp (4096 rows x 64) ----------------
__global__ __launch_bounds__(256) void k_normalize(float* __restrict__ cp) {
  int row = blockIdx.x * 4 + (threadIdx.x >> 6);
  int d = threadIdx.x & 63;
  float x = cp[(size_t)row * 64 + d];
  float ss = x * x;
  #pragma unroll
  for (int off = 32; off; off >>= 1) ss += __shfl_xor(ss, off);
  float nrm = sqrtf(ss);
  cp[(size_t)row * 64 + d] = x / fmaxf(nrm, 1e-12f);
}

// ---------------- centrality[b,n] = x_n.(sum_m x_m) - x_n.x_n ----------------
__global__ __launch_bounds__(512) void k_centrality(const float* __restrict__ cp, float* __restrict__ cent) {
  int b = blockIdx.x;
  int tid = threadIdx.x;
  __shared__ float part[8][64];
  __shared__ float vsum[64];
  int d = tid & 63, g = tid >> 6;
  float sacc = 0.f;
  for (int n = g * 64; n < g * 64 + 64; ++n)
    sacc += cp[((size_t)b * N_ + n) * 64 + d];
  part[g][d] = sacc;
  __syncthreads();
  if (tid < 64) {
    float v = 0.f;
    #pragma unroll
    for (int gg = 0; gg < 8; ++gg) v += part[gg][tid];
    vsum[tid] = v;
  }
  __syncthreads();
  const float* x = cp + ((size_t)b * N_ + tid) * 64;
  float dsum = 0.f, dself = 0.f;
  #pragma unroll
  for (int dd = 0; dd < 64; ++dd) {
    float xv = x[dd];
    dsum += xv * vsum[dd];
    dself += xv * xv;
  }
  cent[b * N_ + tid] = dsum - dself;
}

// ---------------- top-k select + mask + fallback ----------------
__global__ __launch_bounds__(512) void k_select(const float* __restrict__ cent, const int* __restrict__ mask,
                                                int* __restrict__ allowed) {
  int b = blockIdx.x, tid = threadIdx.x;
  __shared__ float sc[512];
  __shared__ int anyflag;
  sc[tid] = cent[b * N_ + tid];
  if (tid == 0) anyflag = 0;
  __syncthreads();
  float v = sc[tid];
  int rank = 0;
  for (int j = 0; j < N_; ++j) {
    float u = sc[j];
    rank += (u > v) || (u == v && j < tid);
  }
  int sel = (rank < KSEL_) && (mask[b * N_ + tid] != 0);
  if (sel) anyflag = 1;
  __syncthreads();
  int outv = sel;
  if (anyflag == 0 && rank == 0) outv = 1;
  allowed[b * N_ + tid] = outv;
}

// ---------------- flash attention, 4 lanes per (query,head), writes bf16 ----------------
__global__ __launch_bounds__(256) void k_attn4(const float* __restrict__ q, const float* __restrict__ Kp,
                                               const float* __restrict__ Vp, const int* __restrict__ allowed,
                                               short* __restrict__ attn_b) {
  __shared__ float Ks[64][68];
  __shared__ float Vs[64][68];
  __shared__ int alw[64];
  int bid = blockIdx.x;
  int qt = bid & 15, h = (bid >> 4) & 7, b = bid >> 7;
  int tid = threadIdx.x;
  int qi = tid >> 2, dg = tid & 3;
  int s = qt * 64 + qi;
  const float4* qp4 = (const float4*)(q + (size_t)(b * S_ + s) * KV_ + h * DH_ + dg * 16);
  float qv[16];
  #pragma unroll
  for (int i = 0; i < 4; ++i) ((float4*)qv)[i] = qp4[i];
  float mval = -1e30f, lval = 0.f;
  float acc[16];
  #pragma unroll
  for (int d = 0; d < 16; ++d) acc[d] = 0.f;

  for (int kc = 0; kc < N_; kc += 64) {
    #pragma unroll
    for (int i = 0; i < 4; ++i) {
      int idx = tid + i * 256;
      int kk = idx >> 4, d4 = (idx & 15) << 2;
      *(float4*)&Ks[kk][d4] = *(const float4*)&Kp[(size_t)(b * N_ + kc + kk) * KV_ + h * DH_ + d4];
      *(float4*)&Vs[kk][d4] = *(const float4*)&Vp[(size_t)(b * N_ + kc + kk) * KV_ + h * DH_ + d4];
    }
    if (tid < 64) alw[tid] = allowed[b * N_ + kc + tid];
    __syncthreads();
    for (int kk = 0; kk < 64; ++kk) {
      if (!alw[kk]) continue;  // exact: exp(-1e9 - m) == 0 in f32
      const float4* kr = (const float4*)&Ks[kk][dg * 16];
      float sc = 0.f;
      #pragma unroll
      for (int i = 0; i < 4; ++i) {
        float4 kvv = kr[i];
        sc += qv[i * 4 + 0] * kvv.x + qv[i * 4 + 1] * kvv.y + qv[i * 4 + 2] * kvv.z + qv[i * 4 + 3] * kvv.w;
      }
      sc += __shfl_xor(sc, 1);
      sc += __shfl_xor(sc, 2);
      sc *= 0.125f;
      float mn = fmaxf(mval, sc);
      float sscale = __expf(mval - mn);
      float p = __expf(sc - mn);
      lval = lval * sscale + p;
      const float4* vr = (const float4*)&Vs[kk][dg * 16];
      #pragma unroll
      for (int i = 0; i < 4; ++i) {
        float4 vv = vr[i];
        acc[i * 4 + 0] = acc[i * 4 + 0] * sscale + p * vv.x;
        acc[i * 4 + 1] = acc[i * 4 + 1] * sscale + p * vv.y;
        acc[i * 4 + 2] = acc[i * 4 + 2] * sscale + p * vv.z;
        acc[i * 4 + 3] = acc[i * 4 + 3] * sscale + p * vv.w;
      }
      mval = mn;
    }
    __syncthreads();
  }
  float inv = 1.0f / lval;
  short* op = attn_b + (size_t)(b * S_ + s) * KV_ + h * DH_ + dg * 16;
  #pragma unroll
  for (int i = 0; i < 4; ++i) {
    short4v o = { f2bf(acc[i * 4 + 0] * inv), f2bf(acc[i * 4 + 1] * inv),
                  f2bf(acc[i * 4 + 2] * inv), f2bf(acc[i * 4 + 3] * inv) };
    *(short4v*)(op + i * 4) = o;
  }
}

extern "C" void kernel_launch(void* const* d_in, const int* in_sizes, int n_in,
                              void* d_out, int out_size, void* d_ws, size_t ws_size,
                              hipStream_t stream) {
  const float* h         = (const float*)d_in[0];
  const float* cond      = (const float*)d_in[1];
  const int*   cond_mask = (const int*)d_in[2];
  const float* Wq = (const float*)d_in[3];
  const float* bq = (const float*)d_in[4];
  const float* Wk = (const float*)d_in[5];
  const float* bk = (const float*)d_in[6];
  const float* Wv = (const float*)d_in[7];
  const float* bv = (const float*)d_in[8];
  const float* Wrk = (const float*)d_in[11];
  const float* brk = (const float*)d_in[12];
  const float* Wo  = (const float*)d_in[13];
  const float* bo  = (const float*)d_in[14];
  float* out = (float*)d_out;

  char* w = (char*)d_ws;
  float* qbuf    = (float*)(w + 0);          // 16,777,216 B  (8192x512 f32)
  float* Kp      = (float*)(w + 16777216);   //  8,388,608 B
  float* Vp      = (float*)(w + 25165824);   //  8,388,608 B
  float* cp      = (float*)(w + 33554432);   //  1,048,576 B
  float* cent    = (float*)(w + 34603008);   //     16,384 B
  int*   allowed = (int*)  (w + 34619392);   //     16,384 B
  short* hT      = (short*)(w + 34635776);   //  4,194,304 B (bf16 8192x256)
  short* cond_b  = (short*)(w + 38830080);   //  4,194,304 B (bf16 4096x512)
  short* attn_b  = (short*)(w + 34635776);   // alias hT+cond_b (both dead by then)
  short* Wq_b    = (short*)(w + 43024384);   //    262,144 B
  short* Wk_b    = (short*)(w + 43286528);   //    524,288 B
  short* Wv_b    = (short*)(w + 43810816);   //    524,288 B
  short* Wo_b    = (short*)(w + 44335104);   //    262,144 B
  float* outtmp  = qbuf;                     // alias (qbuf dead after attention)

  // converts
  k_f32_to_bf16<<<2048, 256, 0, stream>>>(cond, cond_b, 524288);
  k_f32_to_bf16<<<128, 256, 0, stream>>>(Wq, Wq_b, 32768);
  k_f32_to_bf16<<<256, 256, 0, stream>>>(Wk, Wk_b, 65536);
  k_f32_to_bf16<<<256, 256, 0, stream>>>(Wv, Wv_b, 65536);
  k_f32_to_bf16<<<128, 256, 0, stream>>>(Wo, Wo_b, 32768);
  // transpose h -> bf16 (B,S,C)
  k_transpose_h_bf16<<<dim3(S_ / 32, C_ / 32, B_), 256, 0, stream>>>(h, hT);
  // projections (MFMA)
  k_mfma_gemm<<<dim3(64, 4), 256, 0, stream>>>(hT, Wq_b, bq, qbuf, B_ * S_, KV_, C_);
  k_mfma_gemm<<<dim3(32, 4), 256, 0, stream>>>(cond_b, Wk_b, bk, Kp, B_ * N_, KV_, KV_);
  k_mfma_gemm<<<dim3(32, 4), 256, 0, stream>>>(cond_b, Wv_b, bv, Vp, B_ * N_, KV_, KV_);
  // selector path (f32 exact)
  k_gemm_bias<<<dim3(64, 1), 256, 0, stream>>>(cond, Wrk, brk, cp, B_ * N_, REL_, KV_);
  k_normalize<<<(B_ * N_) / 4, 256, 0, stream>>>(cp);
  k_centrality<<<B_, 512, 0, stream>>>(cp, cent);
  k_select<<<B_, 512, 0, stream>>>(cent, cond_mask, allowed);
  // attention (f32 math, bf16 out)
  k_attn4<<<B_ * NH_ * (S_ / 64), 256, 0, stream>>>(qbuf, Kp, Vp, allowed, attn_b);
  // output projection (MFMA) then transpose to (B,C,S)
  k_mfma_gemm<<<dim3(64, 2), 256, 0, stream>>>(attn_b, Wo_b, bo, outtmp, B_ * S_, C_, KV_);
  k_transpose_sc<<<dim3(C_ / 32, S_ / 32, B_), 256, 0, stream>>>(outtmp, out);
}

// Round 3
// 137.113 us; speedup vs baseline: 3.4691x; 1.9716x over previous
//
#include <hip/hip_runtime.h>
#include <math.h>

#define B_ 8
#define C_ 256
#define S_ 1024
#define N_ 512
#define KV_ 512
#define REL_ 64
#define NH_ 8
#define DH_ 64
#define KSEL_ 307

typedef __attribute__((ext_vector_type(8))) short bf16x8;
typedef __attribute__((ext_vector_type(4))) short short4v;
typedef __attribute__((ext_vector_type(4))) float f32x4;

__device__ __forceinline__ short f2bf(float f) {
  unsigned int u = __float_as_uint(f);
  u += 0x7fffu + ((u >> 16) & 1u);
  return (short)(u >> 16);
}

// ---------------- fused f32->bf16 converts (cond + 4 weights) ----------------
__global__ __launch_bounds__(256) void k_convert_all(const float* __restrict__ cond, const float* __restrict__ Wq,
                                                     const float* __restrict__ Wk, const float* __restrict__ Wv,
                                                     const float* __restrict__ Wo, short* __restrict__ cond_b,
                                                     short* __restrict__ Wq_b, short* __restrict__ Wk_b,
                                                     short* __restrict__ Wv_b, short* __restrict__ Wo_b) {
  int blk = blockIdx.x;
  const float* src; short* dst; int base;
  if (blk < 2048)      { src = cond; dst = cond_b; base = blk; }
  else if (blk < 2176) { src = Wq;   dst = Wq_b;   base = blk - 2048; }
  else if (blk < 2432) { src = Wk;   dst = Wk_b;   base = blk - 2176; }
  else if (blk < 2688) { src = Wv;   dst = Wv_b;   base = blk - 2432; }
  else                 { src = Wo;   dst = Wo_b;   base = blk - 2688; }
  int i = base * 256 + threadIdx.x;
  float4 v = ((const float4*)src)[i];
  short4v o = { f2bf(v.x), f2bf(v.y), f2bf(v.z), f2bf(v.w) };
  ((short4v*)dst)[i] = o;
}

// ---------------- transpose h: (B,C,S) f32 -> (B,S,C) bf16 ----------------
__global__ __launch_bounds__(256) void k_transpose_h_bf16(const float* __restrict__ h, short* __restrict__ hT) {
  __shared__ float tile[32][33];
  int b = blockIdx.z;
  int s0 = blockIdx.x * 32, c0 = blockIdx.y * 32;
  int x = threadIdx.x & 31, y0 = threadIdx.x >> 5;
  #pragma unroll
  for (int y = y0; y < 32; y += 8)
    tile[y][x] = h[((size_t)(b * C_ + c0 + y)) * S_ + s0 + x];
  __syncthreads();
  #pragma unroll
  for (int y = y0; y < 32; y += 8)
    hT[((size_t)(b * S_ + s0 + y)) * C_ + c0 + x] = f2bf(tile[x][y]);
}

// ---------------- transpose V: (B,N,KV) bf16 -> (B,H,D,N) bf16 ----------------
__global__ __launch_bounds__(256) void k_transpose_v(const short* __restrict__ Vb, short* __restrict__ Vt) {
  __shared__ unsigned short t[32][33];
  int bh = blockIdx.z, b = bh >> 3, h = bh & 7;
  int n0 = blockIdx.x * 32, d0 = blockIdx.y * 32;
  int tid = threadIdx.x;
  #pragma unroll
  for (int i = 0; i < 4; ++i) {
    int idx = tid + i * 256;
    int n = idx >> 5, d = idx & 31;
    t[n][d] = ((const unsigned short*)Vb)[(size_t)(b * N_ + n0 + n) * KV_ + h * DH_ + d0 + d];
  }
  __syncthreads();
  #pragma unroll
  for (int i = 0; i < 4; ++i) {
    int idx = tid + i * 256;
    int d = idx >> 5, n = idx & 31;
    ((unsigned short*)Vt)[((size_t)((b * NH_ + h) * DH_) + d0 + d) * N_ + n0 + n] = t[n][d];
  }
}

// ---------------- MFMA bf16 GEMM ----------------
// MODE 0: bf16 store Cout[row*Nout+col], bias[col]
// MODE 1: f32 store out[((col>>10)*C_ + row)*S_ + (col&1023)], bias[row]  (out-projection, outT)
#define BM 128
#define BN 128
#define BKG 64
template<int MODE>
__global__ __launch_bounds__(256) void k_mfma_gemm(const short* __restrict__ A, const short* __restrict__ W,
                                                   const float* __restrict__ bias, void* __restrict__ Cout,
                                                   int M, int Nout, int Kd) {
  __shared__ short As[BM][BKG];
  __shared__ short Bs[BN][BKG];
  int tid = threadIdx.x;
  int lane = tid & 63, wid = tid >> 6;
  int wr = wid >> 1, wc = wid & 1;
  size_t bm = (size_t)blockIdx.x * BM, bn = (size_t)blockIdx.y * BN;
  f32x4 acc[4][4] = {};
  int lrow = lane >> 3;
  int lcol = (lane & 7) * 8;
  for (int k0 = 0; k0 < Kd; k0 += BKG) {
    #pragma unroll
    for (int i = 0; i < 4; ++i) {
      int r0 = wid * 32 + i * 8;
      const short* gp = A + (bm + r0 + lrow) * Kd + k0 + lcol;
      __builtin_amdgcn_global_load_lds((const __attribute__((address_space(1))) void*)gp,
                                       (__attribute__((address_space(3))) void*)&As[r0][0], 16, 0, 0);
    }
    #pragma unroll
    for (int i = 0; i < 4; ++i) {
      int r0 = wid * 32 + i * 8;
      const short* gp = W + (bn + r0 + lrow) * Kd + k0 + lcol;
      __builtin_amdgcn_global_load_lds((const __attribute__((address_space(1))) void*)gp,
                                       (__attribute__((address_space(3))) void*)&Bs[r0][0], 16, 0, 0);
    }
    asm volatile("s_waitcnt vmcnt(0)" ::: "memory");
    __syncthreads();
    #pragma unroll
    for (int kk = 0; kk < BKG; kk += 32) {
      bf16x8 a[4], b[4];
      #pragma unroll
      for (int m = 0; m < 4; ++m)
        a[m] = *(const bf16x8*)&As[wr * 64 + m * 16 + (lane & 15)][kk + (lane >> 4) * 8];
      #pragma unroll
      for (int n = 0; n < 4; ++n)
        b[n] = *(const bf16x8*)&Bs[wc * 64 + n * 16 + (lane & 15)][kk + (lane >> 4) * 8];
      #pragma unroll
      for (int m = 0; m < 4; ++m)
        #pragma unroll
        for (int n = 0; n < 4; ++n)
          acc[m][n] = __builtin_amdgcn_mfma_f32_16x16x32_bf16(a[m], b[n], acc[m][n], 0, 0, 0);
    }
    __syncthreads();
  }
  int c0 = lane & 15, r0q = lane >> 4;
  #pragma unroll
  for (int n = 0; n < 4; ++n) {
    size_t col = bn + wc * 64 + n * 16 + c0;
    #pragma unroll
    for (int m = 0; m < 4; ++m) {
      #pragma unroll
      for (int j = 0; j < 4; ++j) {
        size_t row = bm + wr * 64 + m * 16 + r0q * 4 + j;
        if (MODE == 0) {
          ((short*)Cout)[row * Nout + col] = f2bf(acc[m][n][j] + bias[col]);
        } else {
          ((float*)Cout)[((col >> 10) * C_ + row) * S_ + (col & (S_ - 1))] = acc[m][n][j] + bias[row];
        }
      }
    }
  }
}

// ---------------- selector rel-proj: f32 split-K GEMM (4096x64, K=512 over 4 slices) ----------------
__global__ __launch_bounds__(256) void k_gemm_rel(const float* __restrict__ A, const float* __restrict__ W,
                                                  float* __restrict__ Cpart) {
  __shared__ float As[64][17];
  __shared__ float Bs[64][17];
  int tid = threadIdx.x;
  int tm = (tid >> 4) << 2;
  int tn = (tid & 15) << 2;
  int bm = blockIdx.x * 64;
  int kb = blockIdx.y;
  float acc[4][4] = {};
  for (int k0 = kb * 128; k0 < kb * 128 + 128; k0 += 16) {
    #pragma unroll
    for (int i = 0; i < 4; ++i) {
      int idx = tid + i * 256;
      int r = idx >> 4, k = idx & 15;
      As[r][k] = A[(size_t)(bm + r) * KV_ + k0 + k];
      Bs[r][k] = W[(size_t)r * KV_ + k0 + k];
    }
    __syncthreads();
    #pragma unroll
    for (int k = 0; k < 16; ++k) {
      float a[4], bb[4];
      #pragma unroll
      for (int x = 0; x < 4; ++x) { a[x] = As[tm + x][k]; bb[x] = Bs[tn + x][k]; }
      #pragma unroll
      for (int x = 0; x < 4; ++x)
        #pragma unroll
        for (int y = 0; y < 4; ++y)
          acc[x][y] += a[x] * bb[y];
    }
    __syncthreads();
  }
  #pragma unroll
  for (int x = 0; x < 4; ++x)
    #pragma unroll
    for (int y = 0; y < 4; ++y)
      Cpart[(size_t)kb * 262144 + (size_t)(bm + tm + x) * 64 + tn + y] = acc[x][y];
}

// ---------------- reduce partials + bias + normalize ----------------
__global__ __launch_bounds__(256) void k_normalize_fused(const float* __restrict__ part, const float* __restrict__ brk,
                                                         float* __restrict__ cp) {
  int row = blockIdx.x * 4 + (threadIdx.x >> 6);
  int d = threadIdx.x & 63;
  size_t off = (size_t)row * 64 + d;
  float x = part[off] + part[262144 + off] + part[524288 + off] + part[786432 + off] + brk[d];
  float ss = x * x;
  #pragma unroll
  for (int o = 32; o; o >>= 1) ss += __shfl_xor(ss, o);
  cp[off] = x / fmaxf(sqrtf(ss), 1e-12f);
}

// ---------------- centrality + top-k select + mask + fallback ----------------
__global__ __launch_bounds__(512) void k_centrality_select(const float* __restrict__ cp, const int* __restrict__ mask,
                                                           int* __restrict__ allowed) {
  int b = blockIdx.x, tid = threadIdx.x;
  __shared__ float part[8][64];
  __shared__ float vsum[64];
  __shared__ float sc[512];
  __shared__ int anyflag;
  int d = tid & 63, g = tid >> 6;
  float sacc = 0.f;
  for (int n = g * 64; n < g * 64 + 64; ++n)
    sacc += cp[((size_t)b * N_ + n) * 64 + d];
  part[g][d] = sacc;
  if (tid == 0) anyflag = 0;
  __syncthreads();
  if (tid < 64) {
    float v = 0.f;
    #pragma unroll
    for (int gg = 0; gg < 8; ++gg) v += part[gg][tid];
    vsum[tid] = v;
  }
  __syncthreads();
  const float* x = cp + ((size_t)b * N_ + tid) * 64;
  float dsum = 0.f, dself = 0.f;
  #pragma unroll
  for (int dd = 0; dd < 64; ++dd) {
    float xv = x[dd];
    dsum += xv * vsum[dd];
    dself += xv * xv;
  }
  sc[tid] = dsum - dself;
  __syncthreads();
  float v = sc[tid];
  int rank = 0;
  for (int j = 0; j < N_; ++j) {
    float u = sc[j];
    rank += (u > v) || (u == v && j < tid);
  }
  int sel = (rank < KSEL_) && (mask[b * N_ + tid] != 0);
  if (sel) anyflag = 1;
  __syncthreads();
  int outv = sel;
  if (anyflag == 0 && rank == 0) outv = 1;
  allowed[b * N_ + tid] = outv;
}

// ---------------- stage a 64x64 bf16 tile into LDS, XOR-swizzled via pre-swizzled source ----------------
__device__ __forceinline__ void stage_tile64(const short* gRowBase, int gStride, short* ldsBase, int wid, int lane) {
  int sub = lane >> 3;                       // 0..7 : row within 8-row group
  int colE = ((lane & 7) ^ sub) * 8;         // pre-swizzled source column (elems)
  #pragma unroll
  for (int i = 0; i < 2; ++i) {
    int r = wid * 16 + i * 8 + sub;
    const short* gp = gRowBase + (size_t)r * gStride + colE;
    __builtin_amdgcn_global_load_lds((const __attribute__((address_space(1))) void*)gp,
                                     (__attribute__((address_space(3))) void*)(ldsBase + wid * 1024 + i * 512),
                                     16, 0, 0);
  }
}

// ---------------- MFMA flash attention ----------------
// block = (qtile 64 rows, head, batch); 4 waves x 16 q-rows.
// QK^T: mfma(K,Q) -> D[key][q] (q = lane&15, lane-local softmax stats)
// PV:   mfma(Vt,P) -> D[d][q]
__global__ __launch_bounds__(256, 4) void k_attn_mfma(const short* __restrict__ qb, const short* __restrict__ Kb,
                                                      const short* __restrict__ Vt, const int* __restrict__ allowed,
                                                      short* __restrict__ attn_b) {
  __shared__ short Qs[4096];
  __shared__ short Ks[4096];
  __shared__ short Vs[4096];
  __shared__ short Ps[4096];
  __shared__ int alwLds[64];
  int qt = blockIdx.x, h = blockIdx.y, b = blockIdx.z;
  int tid = threadIdx.x, lane = tid & 63, wid = tid >> 6;
  int hi = lane >> 4, q = lane & 15;
  int s0 = qt * 64;
  const short* Qg = qb + ((size_t)(b * S_ + s0) * KV_ + h * DH_);
  const short* Kg = Kb + ((size_t)(b * N_) * KV_ + h * DH_);
  const short* Vg = Vt + ((size_t)((b * NH_ + h) * DH_) * N_);

  stage_tile64(Qg, KV_, Qs, wid, lane);
  stage_tile64(Kg, KV_, Ks, wid, lane);
  stage_tile64(Vg, N_, Vs, wid, lane);
  if (wid == 0)
    __builtin_amdgcn_global_load_lds((const __attribute__((address_space(1))) void*)(allowed + b * N_ + lane),
                                     (__attribute__((address_space(3))) void*)alwLds, 4, 0, 0);
  asm volatile("s_waitcnt vmcnt(0)" ::: "memory");
  __syncthreads();

  int swz = (lane & 7) << 3;
  int qsw = (q & 7) << 3;  // == swz (q&7 == lane&7), kept for clarity
  bf16x8 qf0 = *(const bf16x8*)&Qs[(wid * 16 + q) * 64 + ((hi * 8) ^ swz)];
  bf16x8 qf1 = *(const bf16x8*)&Qs[(wid * 16 + q) * 64 + ((32 + hi * 8) ^ swz)];

  float m = -1e30f, l = 0.f;
  f32x4 o[4] = {};

  for (int t = 0; t < 8; ++t) {
    // ---- QK^T ----
    f32x4 pv[4];
    #pragma unroll
    for (int kf = 0; kf < 4; ++kf) {
      bf16x8 k0 = *(const bf16x8*)&Ks[(kf * 16 + q) * 64 + ((hi * 8) ^ swz)];
      bf16x8 k1 = *(const bf16x8*)&Ks[(kf * 16 + q) * 64 + ((32 + hi * 8) ^ swz)];
      f32x4 z = {0.f, 0.f, 0.f, 0.f};
      pv[kf] = __builtin_amdgcn_mfma_f32_16x16x32_bf16(k0, qf0, z, 0, 0, 0);
      pv[kf] = __builtin_amdgcn_mfma_f32_16x16x32_bf16(k1, qf1, pv[kf], 0, 0, 0);
    }
    // ---- mask + online softmax (per-lane row q) ----
    float sv[16];
    #pragma unroll
    for (int kf = 0; kf < 4; ++kf) {
      int4 aw = *(const int4*)&alwLds[kf * 16 + hi * 4];
      const int* awp = (const int*)&aw;
      #pragma unroll
      for (int r = 0; r < 4; ++r)
        sv[kf * 4 + r] = awp[r] ? pv[kf][r] * 0.125f : -3e38f;
    }
    float tmax = sv[0];
    #pragma unroll
    for (int i = 1; i < 16; ++i) tmax = fmaxf(tmax, sv[i]);
    tmax = fmaxf(tmax, __shfl_xor(tmax, 16));
    tmax = fmaxf(tmax, __shfl_xor(tmax, 32));
    float mnew = fmaxf(m, tmax);
    float scale = __expf(m - mnew);
    float psum = 0.f;
    #pragma unroll
    for (int i = 0; i < 16; ++i) { sv[i] = __expf(sv[i] - mnew); psum += sv[i]; }
    psum += __shfl_xor(psum, 16);
    psum += __shfl_xor(psum, 32);
    l = l * scale + psum;
    m = mnew;
    #pragma unroll
    for (int df = 0; df < 4; ++df) {
      o[df][0] *= scale; o[df][1] *= scale; o[df][2] *= scale; o[df][3] *= scale;
    }
    // ---- P -> per-wave LDS (bf16, swizzled) ----
    int pbase = wid * 1024 + q * 64;
    #pragma unroll
    for (int kf = 0; kf < 4; ++kf) {
      short4v pk = { f2bf(sv[kf * 4 + 0]), f2bf(sv[kf * 4 + 1]), f2bf(sv[kf * 4 + 2]), f2bf(sv[kf * 4 + 3]) };
      *(short4v*)&Ps[pbase + ((kf * 16 + hi * 4) ^ qsw)] = pk;
    }
    // ---- PV ----
    #pragma unroll
    for (int ks = 0; ks < 2; ++ks) {
      bf16x8 pb = *(const bf16x8*)&Ps[pbase + ((ks * 32 + hi * 8) ^ qsw)];
      #pragma unroll
      for (int df = 0; df < 4; ++df) {
        bf16x8 vf = *(const bf16x8*)&Vs[(df * 16 + q) * 64 + ((ks * 32 + hi * 8) ^ swz)];
        o[df] = __builtin_amdgcn_mfma_f32_16x16x32_bf16(vf, pb, o[df], 0, 0, 0);
      }
    }
    __syncthreads();
    if (t < 7) {
      int kc = (t + 1) * 64;
      stage_tile64(Kg + (size_t)kc * KV_, KV_, Ks, wid, lane);
      stage_tile64(Vg + kc, N_, Vs, wid, lane);
      if (wid == 0)
        __builtin_amdgcn_global_load_lds((const __attribute__((address_space(1))) void*)(allowed + b * N_ + kc + lane),
                                         (__attribute__((address_space(3))) void*)alwLds, 4, 0, 0);
      asm volatile("s_waitcnt vmcnt(0)" ::: "memory");
      __syncthreads();
    }
  }
  float inv = 1.0f / l;
  short* op = attn_b + ((size_t)(b * S_ + s0 + wid * 16 + q) * KV_ + h * DH_);
  #pragma unroll
  for (int df = 0; df < 4; ++df) {
    short4v ov = { f2bf(o[df][0] * inv), f2bf(o[df][1] * inv), f2bf(o[df][2] * inv), f2bf(o[df][3] * inv) };
    *(short4v*)&op[df * 16 + hi * 4] = ov;
  }
}

extern "C" void kernel_launch(void* const* d_in, const int* in_sizes, int n_in,
                              void* d_out, int out_size, void* d_ws, size_t ws_size,
                              hipStream_t stream) {
  const float* h         = (const float*)d_in[0];
  const float* cond      = (const float*)d_in[1];
  const int*   cond_mask = (const int*)d_in[2];
  const float* Wq = (const float*)d_in[3];
  const float* bq = (const float*)d_in[4];
  const float* Wk = (const float*)d_in[5];
  const float* bk = (const float*)d_in[6];
  const float* Wv = (const float*)d_in[7];
  const float* bv = (const float*)d_in[8];
  const float* Wrk = (const float*)d_in[11];
  const float* brk = (const float*)d_in[12];
  const float* Wo  = (const float*)d_in[13];
  const float* bo  = (const float*)d_in[14];
  float* out = (float*)d_out;

  char* w = (char*)d_ws;
  short* qb      = (short*)(w + 0);           //  8,388,608
  short* Kb      = (short*)(w + 8388608);     //  4,194,304
  short* Vb      = (short*)(w + 12582912);    //  4,194,304
  short* Vt      = (short*)(w + 16777216);    //  4,194,304
  short* attn_b  = (short*)(w + 20971520);    //  8,388,608
  short* hT      = (short*)(w + 29360128);    //  4,194,304
  short* cond_b  = (short*)(w + 33554432);    //  4,194,304
  float* cp_part = (float*)(w + 37748736);    //  4,194,304
  float* cp      = (float*)(w + 41943040);    //  1,048,576
  int*   allowed = (int*)  (w + 42991616);    //     16,384
  short* Wq_b    = (short*)(w + 43008000);    //    262,144
  short* Wk_b    = (short*)(w + 43270144);    //    524,288
  short* Wv_b    = (short*)(w + 43794432);    //    524,288
  short* Wo_b    = (short*)(w + 44318720);    //    262,144

  k_convert_all<<<2816, 256, 0, stream>>>(cond, Wq, Wk, Wv, Wo, cond_b, Wq_b, Wk_b, Wv_b, Wo_b);
  k_transpose_h_bf16<<<dim3(32, 8, 8), 256, 0, stream>>>(h, hT);
  // projections -> bf16
  k_mfma_gemm<0><<<dim3(64, 4), 256, 0, stream>>>(hT, Wq_b, bq, qb, B_ * S_, KV_, C_);
  k_mfma_gemm<0><<<dim3(32, 4), 256, 0, stream>>>(cond_b, Wk_b, bk, Kb, B_ * N_, KV_, KV_);
  k_mfma_gemm<0><<<dim3(32, 4), 256, 0, stream>>>(cond_b, Wv_b, bv, Vb, B_ * N_, KV_, KV_);
  // selector path (f32 exact)
  k_gemm_rel<<<dim3(64, 4), 256, 0, stream>>>(cond, Wrk, cp_part);
  k_normalize_fused<<<1024, 256, 0, stream>>>(cp_part, brk, cp);
  k_centrality_select<<<8, 512, 0, stream>>>(cp, cond_mask, allowed);
  // V transpose for PV MFMA operand
  k_transpose_v<<<dim3(16, 2, 64), 256, 0, stream>>>(Vb, Vt);
  // attention
  k_attn_mfma<<<dim3(16, 8, 8), 256, 0, stream>>>(qb, Kb, Vt, allowed, attn_b);
  // output projection: outT = Wo @ attnT stored directly as (B,C,S)
  k_mfma_gemm<1><<<dim3(2, 64), 256, 0, stream>>>(Wo_b, attn_b, bo, out, C_, B_ * S_, KV_);
}

// Round 4
// 130.044 us; speedup vs baseline: 3.6576x; 1.0544x over previous
//
#include <hip/hip_runtime.h>
#include <math.h>

#define B_ 8
#define C_ 256
#define S_ 1024
#define N_ 512
#define KV_ 512
#define REL_ 64
#define NH_ 8
#define DH_ 64
#define KSEL_ 307

#define BM 128
#define BN 128
#define BKG 64

typedef __attribute__((ext_vector_type(8))) short bf16x8;
typedef __attribute__((ext_vector_type(4))) short short4v;
typedef __attribute__((ext_vector_type(4))) float f32x4;

__device__ __forceinline__ short f2bf(float f) {
  unsigned int u = __float_as_uint(f);
  u += 0x7fffu + ((u >> 16) & 1u);
  return (short)(u >> 16);
}

// ==================== L1: converts + h-transpose + rel-proj ====================
__global__ __launch_bounds__(256) void k_prep(const float* __restrict__ cond, const float* __restrict__ Wq,
                                              const float* __restrict__ Wk, const float* __restrict__ Wv,
                                              const float* __restrict__ Wo, const float* __restrict__ h,
                                              const float* __restrict__ Wrk,
                                              short* __restrict__ cond_b, short* __restrict__ Wq_b,
                                              short* __restrict__ Wk_b, short* __restrict__ Wv_b,
                                              short* __restrict__ Wo_b, short* __restrict__ hT,
                                              float* __restrict__ cp_part) {
  __shared__ float fs[2176];
  int blk = blockIdx.x, tid = threadIdx.x;
  if (blk < 2816) {
    // ---- f32 -> bf16 converts ----
    const float* src; short* dst; int base;
    if (blk < 2048)      { src = cond; dst = cond_b; base = blk; }
    else if (blk < 2176) { src = Wq;   dst = Wq_b;   base = blk - 2048; }
    else if (blk < 2432) { src = Wk;   dst = Wk_b;   base = blk - 2176; }
    else if (blk < 2688) { src = Wv;   dst = Wv_b;   base = blk - 2432; }
    else                 { src = Wo;   dst = Wo_b;   base = blk - 2688; }
    int i = base * 256 + tid;
    float4 v = ((const float4*)src)[i];
    short4v o = { f2bf(v.x), f2bf(v.y), f2bf(v.z), f2bf(v.w) };
    ((short4v*)dst)[i] = o;
  } else if (blk < 4864) {
    // ---- transpose h: (B,C,S) f32 -> (B,S,C) bf16 ----
    int i = blk - 2816;
    int s0 = (i & 31) * 32, c0 = ((i >> 5) & 7) * 32, b = i >> 8;
    int x = tid & 31, y0 = tid >> 5;
    #pragma unroll
    for (int y = y0; y < 32; y += 8)
      fs[y * 33 + x] = h[((size_t)(b * C_ + c0 + y)) * S_ + s0 + x];
    __syncthreads();
    #pragma unroll
    for (int y = y0; y < 32; y += 8)
      hT[((size_t)(b * S_ + s0 + y)) * C_ + c0 + x] = f2bf(fs[x * 33 + y]);
  } else {
    // ---- rel-proj f32 split-K: cp_part[kb][row][64] ----
    int i = blk - 4864;
    int bm = (i & 63) * 64, kb = i >> 6;
    float* As = fs;          // 64x17
    float* Bs = fs + 1088;   // 64x17
    int tm = (tid >> 4) << 2, tn = (tid & 15) << 2;
    float acc[4][4] = {};
    for (int k0 = kb * 128; k0 < kb * 128 + 128; k0 += 16) {
      #pragma unroll
      for (int ii = 0; ii < 4; ++ii) {
        int idx = tid + ii * 256;
        int r = idx >> 4, k = idx & 15;
        As[r * 17 + k] = cond[(size_t)(bm + r) * KV_ + k0 + k];
        Bs[r * 17 + k] = Wrk[(size_t)r * KV_ + k0 + k];
      }
      __syncthreads();
      #pragma unroll
      for (int k = 0; k < 16; ++k) {
        float a[4], bb[4];
        #pragma unroll
        for (int x = 0; x < 4; ++x) { a[x] = As[(tm + x) * 17 + k]; bb[x] = Bs[(tn + x) * 17 + k]; }
        #pragma unroll
        for (int x = 0; x < 4; ++x)
          #pragma unroll
          for (int y = 0; y < 4; ++y)
            acc[x][y] += a[x] * bb[y];
      }
      __syncthreads();
    }
    #pragma unroll
    for (int x = 0; x < 4; ++x)
      #pragma unroll
      for (int y = 0; y < 4; ++y)
        cp_part[(size_t)kb * 262144 + (size_t)(bm + tm + x) * 64 + tn + y] = acc[x][y];
  }
}

// ==================== MFMA GEMM body ====================
// MODE 0: bf16 store Cout[row*Nout+col], bias[col]
// MODE 1: f32 store out[((col>>10)*C_ + row)*S_ + (col&1023)], bias[row]   (out-projection)
// MODE 2: bf16 V^T store Vt[((b*8+h)*64+d)*512 + n], bias[col]             (V-projection)
template<int MODE>
__device__ __forceinline__ void gemm_body(const short* __restrict__ A, const short* __restrict__ W,
                                          const float* __restrict__ bias, void* __restrict__ Cout,
                                          short* As, short* Bs, int bx, int by, int Kd, int Nout) {
  int tid = threadIdx.x;
  int lane = tid & 63, wid = tid >> 6;
  int wr = wid >> 1, wc = wid & 1;
  size_t bm = (size_t)bx * BM, bn = (size_t)by * BN;
  f32x4 acc[4][4] = {};
  int lrow = lane >> 3;
  int lcol = (lane & 7) * 8;
  for (int k0 = 0; k0 < Kd; k0 += BKG) {
    #pragma unroll
    for (int i = 0; i < 4; ++i) {
      int r0 = wid * 32 + i * 8;
      const short* gp = A + (bm + r0 + lrow) * Kd + k0 + lcol;
      __builtin_amdgcn_global_load_lds((const __attribute__((address_space(1))) void*)gp,
                                       (__attribute__((address_space(3))) void*)(As + r0 * BKG), 16, 0, 0);
    }
    #pragma unroll
    for (int i = 0; i < 4; ++i) {
      int r0 = wid * 32 + i * 8;
      const short* gp = W + (bn + r0 + lrow) * Kd + k0 + lcol;
      __builtin_amdgcn_global_load_lds((const __attribute__((address_space(1))) void*)gp,
                                       (__attribute__((address_space(3))) void*)(Bs + r0 * BKG), 16, 0, 0);
    }
    asm volatile("s_waitcnt vmcnt(0)" ::: "memory");
    __syncthreads();
    #pragma unroll
    for (int kk = 0; kk < BKG; kk += 32) {
      bf16x8 a[4], b[4];
      #pragma unroll
      for (int m = 0; m < 4; ++m)
        a[m] = *(const bf16x8*)(As + (wr * 64 + m * 16 + (lane & 15)) * BKG + kk + (lane >> 4) * 8);
      #pragma unroll
      for (int n = 0; n < 4; ++n)
        b[n] = *(const bf16x8*)(Bs + (wc * 64 + n * 16 + (lane & 15)) * BKG + kk + (lane >> 4) * 8);
      #pragma unroll
      for (int m = 0; m < 4; ++m)
        #pragma unroll
        for (int n = 0; n < 4; ++n)
          acc[m][n] = __builtin_amdgcn_mfma_f32_16x16x32_bf16(a[m], b[n], acc[m][n], 0, 0, 0);
    }
    __syncthreads();
  }
  int c0 = lane & 15, r0q = lane >> 4;
  #pragma unroll
  for (int n = 0; n < 4; ++n) {
    size_t col = bn + wc * 64 + n * 16 + c0;
    #pragma unroll
    for (int m = 0; m < 4; ++m) {
      #pragma unroll
      for (int j = 0; j < 4; ++j) {
        size_t row = bm + wr * 64 + m * 16 + r0q * 4 + j;
        if (MODE == 0) {
          ((short*)Cout)[row * Nout + col] = f2bf(acc[m][n][j] + bias[col]);
        } else if (MODE == 1) {
          ((float*)Cout)[((col >> 10) * C_ + row) * S_ + (col & (S_ - 1))] = acc[m][n][j] + bias[row];
        } else {
          // row = b*512 + n_idx ; col = h*64 + d
          ((short*)Cout)[(((row >> 9) * 8 + (col >> 6)) * 64 + (col & 63)) * (size_t)N_ + (row & 511)] =
              f2bf(acc[m][n][j] + bias[col]);
        }
      }
    }
  }
}

// ==================== L2: q/K/V projections + normalize ====================
__global__ __launch_bounds__(256) void k_fused_proj(const short* __restrict__ hT, const short* __restrict__ cond_b,
                                                    const short* __restrict__ Wq_b, const short* __restrict__ Wk_b,
                                                    const short* __restrict__ Wv_b,
                                                    const float* __restrict__ bq, const float* __restrict__ bk,
                                                    const float* __restrict__ bv,
                                                    short* __restrict__ qb, short* __restrict__ Kb,
                                                    short* __restrict__ Vt,
                                                    const float* __restrict__ cp_part, const float* __restrict__ brk,
                                                    float* __restrict__ cp) {
  __shared__ short smem[BM * BKG * 2];
  int blk = blockIdx.x;
  if (blk < 256) {
    gemm_body<0>(hT, Wq_b, bq, qb, smem, smem + BM * BKG, blk & 63, blk >> 6, C_, KV_);
  } else if (blk < 384) {
    int i = blk - 256;
    gemm_body<0>(cond_b, Wk_b, bk, Kb, smem, smem + BM * BKG, i & 31, i >> 5, KV_, KV_);
  } else if (blk < 512) {
    int i = blk - 384;
    gemm_body<2>(cond_b, Wv_b, bv, Vt, smem, smem + BM * BKG, i & 31, i >> 5, KV_, KV_);
  } else {
    // normalize: reduce split-K partials + bias + L2-normalize rows of cp
    int i = blk - 512;
    int row = i * 4 + (threadIdx.x >> 6);
    int d = threadIdx.x & 63;
    size_t off = (size_t)row * 64 + d;
    float x = cp_part[off] + cp_part[262144 + off] + cp_part[524288 + off] + cp_part[786432 + off] + brk[d];
    float ss = x * x;
    #pragma unroll
    for (int o = 32; o; o >>= 1) ss += __shfl_xor(ss, o);
    cp[off] = x / fmaxf(sqrtf(ss), 1e-12f);
  }
}

// ==================== L3: centrality + top-k + mask + fallback + compaction ====================
__global__ __launch_bounds__(512) void k_centrality_select(const float* __restrict__ cp, const int* __restrict__ mask,
                                                           int* __restrict__ idxb, int* __restrict__ cnt) {
  int b = blockIdx.x, tid = threadIdx.x;
  __shared__ float part[8][64];
  __shared__ float vsum[64];
  __shared__ float sc[512];
  __shared__ int wcnt[8];
  int d = tid & 63, g = tid >> 6;
  float sacc = 0.f;
  for (int n = g * 64; n < g * 64 + 64; ++n)
    sacc += cp[((size_t)b * N_ + n) * 64 + d];
  part[g][d] = sacc;
  __syncthreads();
  if (tid < 64) {
    float v = 0.f;
    #pragma unroll
    for (int gg = 0; gg < 8; ++gg) v += part[gg][tid];
    vsum[tid] = v;
  }
  __syncthreads();
  const float* x = cp + ((size_t)b * N_ + tid) * 64;
  float dsum = 0.f, dself = 0.f;
  #pragma unroll
  for (int dd = 0; dd < 64; ++dd) {
    float xv = x[dd];
    dsum += xv * vsum[dd];
    dself += xv * xv;
  }
  sc[tid] = dsum - dself;
  __syncthreads();
  float v = sc[tid];
  int rank = 0;
  for (int j = 0; j < N_; ++j) {
    float u = sc[j];
    rank += (u > v) || (u == v && j < tid);
  }
  int sel = (rank < KSEL_) && (mask[b * N_ + tid] != 0);
  unsigned long long bal = __ballot(sel);
  if ((tid & 63) == 0) wcnt[g] = __popcll(bal);
  __syncthreads();
  int off = 0, total = 0;
  #pragma unroll
  for (int i = 0; i < 8; ++i) { int c = wcnt[i]; total += c; if (i < g) off += c; }
  int pos = off + __popcll(bal & ((1ull << (tid & 63)) - 1ull));
  if (sel) idxb[b * N_ + pos] = tid;
  if (total == 0 && rank == 0) idxb[b * N_] = tid;  // top-1 fallback
  if (tid == 0) cnt[b] = (total == 0) ? 1 : total;
}

// ==================== L4: gather compact K rows + V^T columns (zero-padded to 64) ====================
__global__ __launch_bounds__(256) void k_gather(const short* __restrict__ Kb, const short* __restrict__ Vt,
                                                const int* __restrict__ idxb, const int* __restrict__ cnt,
                                                short* __restrict__ Kc, short* __restrict__ Vtc) {
  int blk = blockIdx.x, tid = threadIdx.x;
  if (blk < 64) {
    int b = blk >> 3, rg = blk & 7;
    int cv = cnt[b], padded = (cv + 63) & ~63;
    #pragma unroll
    for (int it = 0; it < 16; ++it) {
      int e = it * 256 + tid;
      int r = rg * 64 + (e >> 6);
      int ch = e & 63;
      if (r < padded) {
        int4 val = {0, 0, 0, 0};
        if (r < cv) {
          int src = idxb[b * N_ + r];
          val = *(const int4*)(Kb + ((size_t)(b * N_ + src) * KV_) + ch * 8);
        }
        *(int4*)(Kc + ((size_t)(b * N_ + r) * KV_) + ch * 8) = val;
      }
    }
  } else {
    int i2 = blk - 64;
    int bh = i2 >> 3, dg = i2 & 7;
    int b = bh >> 3;
    int cv = cnt[b], padded = (cv + 63) & ~63;
    #pragma unroll
    for (int it = 0; it < 16; ++it) {
      int e = it * 256 + tid;
      int dd = dg * 8 + (e >> 9);
      int i = e & 511;
      if (i < padded) {
        short vv = 0;
        if (i < cv) vv = Vt[((size_t)bh * 64 + dd) * N_ + idxb[b * N_ + i]];
        Vtc[((size_t)bh * 64 + dd) * N_ + i] = vv;
      }
    }
  }
}

// ==================== stage 64x64 bf16 tile into LDS (XOR-swizzled via pre-swizzled source) ====================
__device__ __forceinline__ void stage_tile64(const short* gRowBase, int gStride, short* ldsBase, int wid, int lane) {
  int sub = lane >> 3;
  int colE = ((lane & 7) ^ sub) * 8;
  #pragma unroll
  for (int i = 0; i < 2; ++i) {
    int r = wid * 16 + i * 8 + sub;
    const short* gp = gRowBase + (size_t)r * gStride + colE;
    __builtin_amdgcn_global_load_lds((const __attribute__((address_space(1))) void*)gp,
                                     (__attribute__((address_space(3))) void*)(ldsBase + wid * 1024 + i * 512),
                                     16, 0, 0);
  }
}

// ==================== L5: MFMA flash attention over compacted keys ====================
#define QK2L 0.18033688f  // 0.125 * log2(e)
__global__ __launch_bounds__(256) void k_attn_mfma(const short* __restrict__ qb, const short* __restrict__ Kc,
                                                   const short* __restrict__ Vtc, const int* __restrict__ cnt,
                                                   short* __restrict__ attn_b) {
  __shared__ short Qs[4096];
  __shared__ short Ks[2][4096];
  __shared__ short Vs[2][4096];
  __shared__ short Ps[4096];
  int qt = blockIdx.x, h = blockIdx.y, b = blockIdx.z;
  int tid = threadIdx.x, lane = tid & 63, wid = tid >> 6;
  int hi = lane >> 4, q = lane & 15;
  int s0 = qt * 64;
  int cntv = cnt[b];
  int nt = (cntv + 63) >> 6;
  const short* Qg = qb + ((size_t)(b * S_ + s0) * KV_ + h * DH_);
  const short* Kg = Kc + ((size_t)(b * N_) * KV_ + h * DH_);
  const short* Vg = Vtc + ((size_t)((b * NH_ + h) * DH_) * N_);

  stage_tile64(Qg, KV_, Qs, wid, lane);
  stage_tile64(Kg, KV_, Ks[0], wid, lane);
  stage_tile64(Vg, N_, Vs[0], wid, lane);
  asm volatile("s_waitcnt vmcnt(0)" ::: "memory");
  __syncthreads();

  int swz = (lane & 7) << 3;
  bf16x8 qf0 = *(const bf16x8*)&Qs[(wid * 16 + q) * 64 + ((hi * 8) ^ swz)];
  bf16x8 qf1 = *(const bf16x8*)&Qs[(wid * 16 + q) * 64 + ((32 + hi * 8) ^ swz)];

  float m = -1e30f, l = 0.f;
  f32x4 o[4] = {};

  for (int t = 0; t < nt; ++t) {
    int cur = t & 1;
    const short* Kcur = Ks[cur];
    const short* Vcur = Vs[cur];
    if (t + 1 < nt) {
      stage_tile64(Kg + (size_t)(t + 1) * 64 * KV_, KV_, Ks[cur ^ 1], wid, lane);
      stage_tile64(Vg + (t + 1) * 64, N_, Vs[cur ^ 1], wid, lane);
    }
    // ---- QK^T (log2-domain scores) ----
    f32x4 pv[4];
    #pragma unroll
    for (int kf = 0; kf < 4; ++kf) {
      bf16x8 k0 = *(const bf16x8*)&Kcur[(kf * 16 + q) * 64 + ((hi * 8) ^ swz)];
      bf16x8 k1 = *(const bf16x8*)&Kcur[(kf * 16 + q) * 64 + ((32 + hi * 8) ^ swz)];
      f32x4 z = {0.f, 0.f, 0.f, 0.f};
      pv[kf] = __builtin_amdgcn_mfma_f32_16x16x32_bf16(k0, qf0, z, 0, 0, 0);
      pv[kf] = __builtin_amdgcn_mfma_f32_16x16x32_bf16(k1, qf1, pv[kf], 0, 0, 0);
    }
    // ---- mask (key >= cnt) + online softmax ----
    float sv[16];
    int kbase = t * 64 + hi * 4;
    #pragma unroll
    for (int kf = 0; kf < 4; ++kf) {
      #pragma unroll
      for (int r = 0; r < 4; ++r)
        sv[kf * 4 + r] = (kbase + kf * 16 + r < cntv) ? pv[kf][r] * QK2L : -1e30f;
    }
    float tmax = sv[0];
    #pragma unroll
    for (int i = 1; i < 16; ++i) tmax = fmaxf(tmax, sv[i]);
    tmax = fmaxf(tmax, __shfl_xor(tmax, 16));
    tmax = fmaxf(tmax, __shfl_xor(tmax, 32));
    float mnew = fmaxf(m, tmax);
    float scale = exp2f(m - mnew);
    float psum = 0.f;
    #pragma unroll
    for (int i = 0; i < 16; ++i) { sv[i] = exp2f(sv[i] - mnew); psum += sv[i]; }
    psum += __shfl_xor(psum, 16);
    psum += __shfl_xor(psum, 32);
    l = l * scale + psum;
    m = mnew;
    #pragma unroll
    for (int df = 0; df < 4; ++df) {
      o[df][0] *= scale; o[df][1] *= scale; o[df][2] *= scale; o[df][3] *= scale;
    }
    // ---- P -> per-wave LDS (bf16, swizzled) ----
    int pbase = wid * 1024 + q * 64;
    #pragma unroll
    for (int kf = 0; kf < 4; ++kf) {
      short4v pk = { f2bf(sv[kf * 4 + 0]), f2bf(sv[kf * 4 + 1]), f2bf(sv[kf * 4 + 2]), f2bf(sv[kf * 4 + 3]) };
      *(short4v*)&Ps[pbase + ((kf * 16 + hi * 4) ^ swz)] = pk;
    }
    // ---- PV ----
    #pragma unroll
    for (int ks = 0; ks < 2; ++ks) {
      bf16x8 pb = *(const bf16x8*)&Ps[pbase + ((ks * 32 + hi * 8) ^ swz)];
      #pragma unroll
      for (int df = 0; df < 4; ++df) {
        bf16x8 vf = *(const bf16x8*)&Vcur[(df * 16 + q) * 64 + ((ks * 32 + hi * 8) ^ swz)];
        o[df] = __builtin_amdgcn_mfma_f32_16x16x32_bf16(vf, pb, o[df], 0, 0, 0);
      }
    }
    asm volatile("s_waitcnt vmcnt(0)" ::: "memory");  // own prefetch landed
    __syncthreads();
  }
  float inv = 1.0f / l;
  short* op = attn_b + ((size_t)(b * S_ + s0 + wid * 16 + q) * KV_ + h * DH_);
  #pragma unroll
  for (int df = 0; df < 4; ++df) {
    short4v ov = { f2bf(o[df][0] * inv), f2bf(o[df][1] * inv), f2bf(o[df][2] * inv), f2bf(o[df][3] * inv) };
    *(short4v*)&op[df * 16 + hi * 4] = ov;
  }
}

// ==================== L6: output projection (stores (B,C,S) directly) ====================
__global__ __launch_bounds__(256) void k_outproj(const short* __restrict__ Wo_b, const short* __restrict__ attn_b,
                                                 const float* __restrict__ bo, float* __restrict__ out) {
  __shared__ short smem[BM * BKG * 2];
  gemm_body<1>(Wo_b, attn_b, bo, out, smem, smem + BM * BKG, blockIdx.x, blockIdx.y, KV_, B_ * S_);
}

extern "C" void kernel_launch(void* const* d_in, const int* in_sizes, int n_in,
                              void* d_out, int out_size, void* d_ws, size_t ws_size,
                              hipStream_t stream) {
  const float* h         = (const float*)d_in[0];
  const float* cond      = (const float*)d_in[1];
  const int*   cond_mask = (const int*)d_in[2];
  const float* Wq = (const float*)d_in[3];
  const float* bq = (const float*)d_in[4];
  const float* Wk = (const float*)d_in[5];
  const float* bk = (const float*)d_in[6];
  const float* Wv = (const float*)d_in[7];
  const float* bv = (const float*)d_in[8];
  const float* Wrk = (const float*)d_in[11];
  const float* brk = (const float*)d_in[12];
  const float* Wo  = (const float*)d_in[13];
  const float* bo  = (const float*)d_in[14];
  float* out = (float*)d_out;

  char* w = (char*)d_ws;
  short* qb      = (short*)(w + 0);          // 8 MB
  short* Kb      = (short*)(w + 8388608);    // 4 MB
  short* Vt      = (short*)(w + 12582912);   // 4 MB
  short* attn_b  = (short*)(w + 16777216);   // 8 MB
  short* hT      = (short*)(w + 25165824);   // 4 MB (dead after L2)
  short* Vtc     = (short*)(w + 25165824);   //   alias hT (written L4)
  short* cond_b  = (short*)(w + 29360128);   // 4 MB
  float* cp_part = (float*)(w + 33554432);   // 4 MB (dead after L2)
  short* Kc      = (short*)(w + 33554432);   //   alias cp_part (written L4)
  float* cp      = (float*)(w + 37748736);   // 1 MB
  int*   idxb    = (int*)  (w + 38797312);   // 16 KB
  int*   cnt     = (int*)  (w + 38813696);   // 64 B
  short* Wq_b    = (short*)(w + 38813760);   // 256 KB
  short* Wk_b    = (short*)(w + 39075904);   // 512 KB
  short* Wv_b    = (short*)(w + 39600192);   // 512 KB
  short* Wo_b    = (short*)(w + 40124480);   // 256 KB

  // L1: converts + h-transpose + selector rel-proj
  k_prep<<<5120, 256, 0, stream>>>(cond, Wq, Wk, Wv, Wo, h, Wrk,
                                   cond_b, Wq_b, Wk_b, Wv_b, Wo_b, hT, cp_part);
  // L2: q/K/V projections (V stored transposed) + normalize
  k_fused_proj<<<1536, 256, 0, stream>>>(hT, cond_b, Wq_b, Wk_b, Wv_b, bq, bk, bv,
                                         qb, Kb, Vt, cp_part, brk, cp);
  // L3: centrality + top-k + compaction
  k_centrality_select<<<8, 512, 0, stream>>>(cp, cond_mask, idxb, cnt);
  // L4: gather compact K / V^T
  k_gather<<<576, 256, 0, stream>>>(Kb, Vt, idxb, cnt, Kc, Vtc);
  // L5: attention over compacted keys
  k_attn_mfma<<<dim3(16, 8, 8), 256, 0, stream>>>(qb, Kc, Vtc, cnt, attn_b);
  // L6: output projection -> (B,C,S)
  k_outproj<<<dim3(2, 64), 256, 0, stream>>>(Wo_b, attn_b, bo, out);
}

// Round 7
// 124.568 us; speedup vs baseline: 3.8184x; 1.0440x over previous
//
#include <hip/hip_runtime.h>
#include <math.h>

#define B_ 8
#define C_ 256
#define S_ 1024
#define N_ 512
#define KV_ 512
#define REL_ 64
#define NH_ 8
#define DH_ 64
#define KSEL_ 307

#define BM 128
#define BN 128
#define BKG 64

typedef __attribute__((ext_vector_type(8))) short bf16x8;
typedef __attribute__((ext_vector_type(4))) short short4v;
typedef __attribute__((ext_vector_type(4))) float f32x4;

__device__ __forceinline__ short f2bf(float f) {
  unsigned int u = __float_as_uint(f);
  u += 0x7fffu + ((u >> 16) & 1u);
  return (short)(u >> 16);
}

// ==================== L1: converts + h-transpose + rel-proj ====================
__global__ __launch_bounds__(256) void k_prep(const float* __restrict__ cond, const float* __restrict__ Wq,
                                              const float* __restrict__ Wk, const float* __restrict__ Wv,
                                              const float* __restrict__ Wo, const float* __restrict__ h,
                                              const float* __restrict__ Wrk,
                                              short* __restrict__ cond_b, short* __restrict__ Wq_b,
                                              short* __restrict__ Wk_b, short* __restrict__ Wv_b,
                                              short* __restrict__ Wo_b, short* __restrict__ hT,
                                              float* __restrict__ cp_part) {
  __shared__ float fs[2176];
  int blk = blockIdx.x, tid = threadIdx.x;
  if (blk < 2816) {
    const float* src; short* dst; int base;
    if (blk < 2048)      { src = cond; dst = cond_b; base = blk; }
    else if (blk < 2176) { src = Wq;   dst = Wq_b;   base = blk - 2048; }
    else if (blk < 2432) { src = Wk;   dst = Wk_b;   base = blk - 2176; }
    else if (blk < 2688) { src = Wv;   dst = Wv_b;   base = blk - 2432; }
    else                 { src = Wo;   dst = Wo_b;   base = blk - 2688; }
    int i = base * 256 + tid;
    float4 v = ((const float4*)src)[i];
    short4v o = { f2bf(v.x), f2bf(v.y), f2bf(v.z), f2bf(v.w) };
    ((short4v*)dst)[i] = o;
  } else if (blk < 4864) {
    int i = blk - 2816;
    int s0 = (i & 31) * 32, c0 = ((i >> 5) & 7) * 32, b = i >> 8;
    int x = tid & 31, y0 = tid >> 5;
    #pragma unroll
    for (int y = y0; y < 32; y += 8)
      fs[y * 33 + x] = h[((size_t)(b * C_ + c0 + y)) * S_ + s0 + x];
    __syncthreads();
    #pragma unroll
    for (int y = y0; y < 32; y += 8)
      hT[((size_t)(b * S_ + s0 + y)) * C_ + c0 + x] = f2bf(fs[x * 33 + y]);
  } else {
    int i = blk - 4864;
    int bm = (i & 63) * 64, kb = i >> 6;
    float* As = fs;
    float* Bs = fs + 1088;
    int tm = (tid >> 4) << 2, tn = (tid & 15) << 2;
    float acc[4][4] = {};
    for (int k0 = kb * 128; k0 < kb * 128 + 128; k0 += 16) {
      #pragma unroll
      for (int ii = 0; ii < 4; ++ii) {
        int idx = tid + ii * 256;
        int r = idx >> 4, k = idx & 15;
        As[r * 17 + k] = cond[(size_t)(bm + r) * KV_ + k0 + k];
        Bs[r * 17 + k] = Wrk[(size_t)r * KV_ + k0 + k];
      }
      __syncthreads();
      #pragma unroll
      for (int k = 0; k < 16; ++k) {
        float a[4], bb[4];
        #pragma unroll
        for (int x = 0; x < 4; ++x) { a[x] = As[(tm + x) * 17 + k]; bb[x] = Bs[(tn + x) * 17 + k]; }
        #pragma unroll
        for (int x = 0; x < 4; ++x)
          #pragma unroll
          for (int y = 0; y < 4; ++y)
            acc[x][y] += a[x] * bb[y];
      }
      __syncthreads();
    }
    #pragma unroll
    for (int x = 0; x < 4; ++x)
      #pragma unroll
      for (int y = 0; y < 4; ++y)
        cp_part[(size_t)kb * 262144 + (size_t)(bm + tm + x) * 64 + tn + y] = acc[x][y];
  }
}

// ==================== MFMA GEMM body ====================
// MODE 0: bf16 store Cout[row*Nout+col], bias[col]
// MODE 1: f32 store out[((col>>10)*C_ + row)*S_ + (col&1023)], bias[row]   (out-projection)
template<int MODE>
__device__ __forceinline__ void gemm_body(const short* __restrict__ A, const short* __restrict__ W,
                                          const float* __restrict__ bias, void* __restrict__ Cout,
                                          short* As, short* Bs, int bx, int by, int Kd, int Nout) {
  int tid = threadIdx.x;
  int lane = tid & 63, wid = tid >> 6;
  int wr = wid >> 1, wc = wid & 1;
  size_t bm = (size_t)bx * BM, bn = (size_t)by * BN;
  f32x4 acc[4][4] = {};
  int lrow = lane >> 3;
  int lcol = (lane & 7) * 8;
  for (int k0 = 0; k0 < Kd; k0 += BKG) {
    #pragma unroll
    for (int i = 0; i < 4; ++i) {
      int r0 = wid * 32 + i * 8;
      const short* gp = A + (bm + r0 + lrow) * Kd + k0 + lcol;
      __builtin_amdgcn_global_load_lds((const __attribute__((address_space(1))) void*)gp,
                                       (__attribute__((address_space(3))) void*)(As + r0 * BKG), 16, 0, 0);
    }
    #pragma unroll
    for (int i = 0; i < 4; ++i) {
      int r0 = wid * 32 + i * 8;
      const short* gp = W + (bn + r0 + lrow) * Kd + k0 + lcol;
      __builtin_amdgcn_global_load_lds((const __attribute__((address_space(1))) void*)gp,
                                       (__attribute__((address_space(3))) void*)(Bs + r0 * BKG), 16, 0, 0);
    }
    asm volatile("s_waitcnt vmcnt(0)" ::: "memory");
    __syncthreads();
    #pragma unroll
    for (int kk = 0; kk < BKG; kk += 32) {
      bf16x8 a[4], b[4];
      #pragma unroll
      for (int m = 0; m < 4; ++m)
        a[m] = *(const bf16x8*)(As + (wr * 64 + m * 16 + (lane & 15)) * BKG + kk + (lane >> 4) * 8);
      #pragma unroll
      for (int n = 0; n < 4; ++n)
        b[n] = *(const bf16x8*)(Bs + (wc * 64 + n * 16 + (lane & 15)) * BKG + kk + (lane >> 4) * 8);
      #pragma unroll
      for (int m = 0; m < 4; ++m)
        #pragma unroll
        for (int n = 0; n < 4; ++n)
          acc[m][n] = __builtin_amdgcn_mfma_f32_16x16x32_bf16(a[m], b[n], acc[m][n], 0, 0, 0);
    }
    __syncthreads();
  }
  int c0 = lane & 15, r0q = lane >> 4;
  #pragma unroll
  for (int n = 0; n < 4; ++n) {
    size_t col = bn + wc * 64 + n * 16 + c0;
    #pragma unroll
    for (int m = 0; m < 4; ++m) {
      #pragma unroll
      for (int j = 0; j < 4; ++j) {
        size_t row = bm + wr * 64 + m * 16 + r0q * 4 + j;
        if (MODE == 0) {
          ((short*)Cout)[row * Nout + col] = f2bf(acc[m][n][j] + bias[col]);
        } else {
          ((float*)Cout)[((col >> 10) * C_ + row) * S_ + (col & (S_ - 1))] = acc[m][n][j] + bias[row];
        }
      }
    }
  }
}

// ==================== L2: q/K/V projections + normalize ====================
__global__ __launch_bounds__(256) void k_fused_proj(const short* __restrict__ hT, const short* __restrict__ cond_b,
                                                    const short* __restrict__ Wq_b, const short* __restrict__ Wk_b,
                                                    const short* __restrict__ Wv_b,
                                                    const float* __restrict__ bq, const float* __restrict__ bk,
                                                    const float* __restrict__ bv,
                                                    short* __restrict__ qb, short* __restrict__ Kb,
                                                    short* __restrict__ Vb,
                                                    const float* __restrict__ cp_part, const float* __restrict__ brk,
                                                    float* __restrict__ cp) {
  __shared__ short smem[BM * BKG * 2];
  int blk = blockIdx.x;
  if (blk < 256) {
    gemm_body<0>(hT, Wq_b, bq, qb, smem, smem + BM * BKG, blk & 63, blk >> 6, C_, KV_);
  } else if (blk < 384) {
    int i = blk - 256;
    gemm_body<0>(cond_b, Wk_b, bk, Kb, smem, smem + BM * BKG, i & 31, i >> 5, KV_, KV_);
  } else if (blk < 512) {
    int i = blk - 384;
    gemm_body<0>(cond_b, Wv_b, bv, Vb, smem, smem + BM * BKG, i & 31, i >> 5, KV_, KV_);
  } else {
    int i = blk - 512;
    int row = i * 4 + (threadIdx.x >> 6);
    int d = threadIdx.x & 63;
    size_t off = (size_t)row * 64 + d;
    float x = cp_part[off] + cp_part[262144 + off] + cp_part[524288 + off] + cp_part[786432 + off] + brk[d];
    float ss = x * x;
    #pragma unroll
    for (int o = 32; o; o >>= 1) ss += __shfl_xor(ss, o);
    cp[off] = x / fmaxf(sqrtf(ss), 1e-12f);
  }
}

// ==================== L3: centrality + top-k + mask + fallback + index compaction ====================
__global__ __launch_bounds__(512) void k_centrality_select(const float* __restrict__ cp, const int* __restrict__ mask,
                                                           int* __restrict__ idxb, int* __restrict__ cnt) {
  int b = blockIdx.x, tid = threadIdx.x;
  __shared__ float part[8][64];
  __shared__ float vsum[64];
  __shared__ float sc[512];
  __shared__ int wcnt[8];
  int d = tid & 63, g = tid >> 6;
  float sacc = 0.f;
  for (int n = g * 64; n < g * 64 + 64; ++n)
    sacc += cp[((size_t)b * N_ + n) * 64 + d];
  part[g][d] = sacc;
  __syncthreads();
  if (tid < 64) {
    float v = 0.f;
    #pragma unroll
    for (int gg = 0; gg < 8; ++gg) v += part[gg][tid];
    vsum[tid] = v;
  }
  __syncthreads();
  const float* x = cp + ((size_t)b * N_ + tid) * 64;
  float dsum = 0.f, dself = 0.f;
  #pragma unroll
  for (int dd = 0; dd < 64; ++dd) {
    float xv = x[dd];
    dsum += xv * vsum[dd];
    dself += xv * xv;
  }
  sc[tid] = dsum - dself;
  __syncthreads();
  float v = sc[tid];
  int rank = 0;
  for (int j = 0; j < N_; ++j) {
    float u = sc[j];
    rank += (u > v) || (u == v && j < tid);
  }
  int sel = (rank < KSEL_) && (mask[b * N_ + tid] != 0);
  unsigned long long bal = __ballot(sel);
  if ((tid & 63) == 0) wcnt[g] = __popcll(bal);
  __syncthreads();
  int off = 0, total = 0;
  #pragma unroll
  for (int i = 0; i < 8; ++i) { int c = wcnt[i]; total += c; if (i < g) off += c; }
  int pos = off + __popcll(bal & ((1ull << (tid & 63)) - 1ull));
  if (sel) idxb[b * N_ + pos] = tid;
  if (total == 0 && rank == 0) idxb[b * N_] = tid;
  if (tid == 0) cnt[b] = (total == 0) ? 1 : total;
}

// ==================== L4: gather compact K rows; gather+transpose V -> Vtc ====================
// blocks 0..63: K rows (zero-padded to 64-multiple)
// blocks 64..575: V per (b,h,ntile): coalesced row gather -> LDS transpose -> coalesced Vtc row write
__global__ __launch_bounds__(256) void k_gather(const short* __restrict__ Kb, const short* __restrict__ Vb,
                                                const int* __restrict__ idxb, const int* __restrict__ cnt,
                                                short* __restrict__ Kc, short* __restrict__ Vtc) {
  __shared__ short t[64][68];
  int blk = blockIdx.x, tid = threadIdx.x;
  if (blk < 64) {
    int b = blk >> 3, rg = blk & 7;
    int cv = cnt[b], padded = (cv + 63) & ~63;
    #pragma unroll
    for (int it = 0; it < 16; ++it) {
      int e = it * 256 + tid;
      int r = rg * 64 + (e >> 6);
      int ch = e & 63;
      if (r < padded) {
        int4 val = {0, 0, 0, 0};
        if (r < cv) {
          int src = idxb[b * N_ + r];
          val = *(const int4*)(Kb + ((size_t)(b * N_ + src) * KV_) + ch * 8);
        }
        *(int4*)(Kc + ((size_t)(b * N_ + r) * KV_) + ch * 8) = val;
      }
    }
  } else {
    int i2 = blk - 64;
    int b = i2 >> 6, h = (i2 >> 3) & 7, ntb = i2 & 7;
    int cv = cnt[b], padded = (cv + 63) & ~63;
    if (ntb * 64 >= padded) return;
    const int* idxp = idxb + b * N_;
    // load gathered rows (coalesced 16B per thread)
    #pragma unroll
    for (int p = 0; p < 2; ++p) {
      int c = p * 256 + tid;
      int rr = c >> 3, dd8 = (c & 7) * 8;
      int r = ntb * 64 + rr;
      short4v z = {0, 0, 0, 0};
      short4v v0 = z, v1 = z;
      if (r < cv) {
        int gi = idxp[r];
        const short* gp = Vb + (size_t)(b * N_ + gi) * KV_ + h * 64 + dd8;
        v0 = *(const short4v*)gp;
        v1 = *(const short4v*)(gp + 4);
      }
      *(short4v*)&t[rr][dd8] = v0;
      *(short4v*)&t[rr][dd8 + 4] = v1;
    }
    __syncthreads();
    // transposed write: Vtc[(b*8+h)*64 + dd][ntb*64 + rr8 .. +8] (coalesced 16B per thread)
    #pragma unroll
    for (int p = 0; p < 2; ++p) {
      int c = p * 256 + tid;
      int dd = c >> 3, rr8 = (c & 7) * 8;
      short4v o0, o1;
      #pragma unroll
      for (int j = 0; j < 4; ++j) o0[j] = t[rr8 + j][dd];
      #pragma unroll
      for (int j = 0; j < 4; ++j) o1[j] = t[rr8 + 4 + j][dd];
      short* op = Vtc + ((size_t)((b * NH_ + h) * DH_) + dd) * N_ + ntb * 64 + rr8;
      *(short4v*)op = o0;
      *(short4v*)(op + 4) = o1;
    }
  }
}

// ==================== stage 64x64 bf16 tile into LDS (XOR-swizzled via pre-swizzled source) ====================
__device__ __forceinline__ void stage_tile64(const short* gRowBase, int gStride, short* ldsBase, int wid, int lane) {
  int sub = lane >> 3;
  int colE = ((lane & 7) ^ sub) * 8;
  #pragma unroll
  for (int i = 0; i < 2; ++i) {
    int r = wid * 16 + i * 8 + sub;
    const short* gp = gRowBase + (size_t)r * gStride + colE;
    __builtin_amdgcn_global_load_lds((const __attribute__((address_space(1))) void*)gp,
                                     (__attribute__((address_space(3))) void*)(ldsBase + wid * 1024 + i * 512),
                                     16, 0, 0);
  }
}

// ==================== L5: MFMA flash attention over compacted keys ====================
#define QK2L 0.18033688f  // 0.125 * log2(e)
__global__ __launch_bounds__(256) void k_attn_mfma(const short* __restrict__ qb, const short* __restrict__ Kc,
                                                   const short* __restrict__ Vtc, const int* __restrict__ cnt,
                                                   short* __restrict__ attn_b) {
  __shared__ short Qs[4096];
  __shared__ short Ks[2][4096];
  __shared__ short Vs[2][4096];
  __shared__ short Ps[4096];
  int qt = blockIdx.x, h = blockIdx.y, b = blockIdx.z;
  int tid = threadIdx.x, lane = tid & 63, wid = tid >> 6;
  int hi = lane >> 4, q = lane & 15;
  int s0 = qt * 64;
  int cntv = cnt[b];
  int nt = (cntv + 63) >> 6;
  const short* Qg = qb + ((size_t)(b * S_ + s0) * KV_ + h * DH_);
  const short* Kg = Kc + ((size_t)(b * N_) * KV_ + h * DH_);
  const short* Vg = Vtc + ((size_t)((b * NH_ + h) * DH_) * N_);

  stage_tile64(Qg, KV_, Qs, wid, lane);
  stage_tile64(Kg, KV_, Ks[0], wid, lane);
  stage_tile64(Vg, N_, Vs[0], wid, lane);
  asm volatile("s_waitcnt vmcnt(0)" ::: "memory");
  __syncthreads();

  int swz = (lane & 7) << 3;
  bf16x8 qf0 = *(const bf16x8*)&Qs[(wid * 16 + q) * 64 + ((hi * 8) ^ swz)];
  bf16x8 qf1 = *(const bf16x8*)&Qs[(wid * 16 + q) * 64 + ((32 + hi * 8) ^ swz)];

  float m = -1e30f, l = 0.f;
  f32x4 o[4] = {};

  for (int t = 0; t < nt; ++t) {
    int cur = t & 1;
    const short* Kcur = Ks[cur];
    const short* Vcur = Vs[cur];
    if (t + 1 < nt) {
      stage_tile64(Kg + (size_t)(t + 1) * 64 * KV_, KV_, Ks[cur ^ 1], wid, lane);
      stage_tile64(Vg + (t + 1) * 64, N_, Vs[cur ^ 1], wid, lane);
    }
    // ---- QK^T ----
    f32x4 pv[4];
    __builtin_amdgcn_s_setprio(1);
    #pragma unroll
    for (int kf = 0; kf < 4; ++kf) {
      bf16x8 k0 = *(const bf16x8*)&Kcur[(kf * 16 + q) * 64 + ((hi * 8) ^ swz)];
      bf16x8 k1 = *(const bf16x8*)&Kcur[(kf * 16 + q) * 64 + ((32 + hi * 8) ^ swz)];
      f32x4 z = {0.f, 0.f, 0.f, 0.f};
      pv[kf] = __builtin_amdgcn_mfma_f32_16x16x32_bf16(k0, qf0, z, 0, 0, 0);
      pv[kf] = __builtin_amdgcn_mfma_f32_16x16x32_bf16(k1, qf1, pv[kf], 0, 0, 0);
    }
    __builtin_amdgcn_s_setprio(0);
    // ---- mask + online softmax (log2 domain) ----
    float sv[16];
    int kbase = t * 64 + hi * 4;
    #pragma unroll
    for (int kf = 0; kf < 4; ++kf) {
      #pragma unroll
      for (int r = 0; r < 4; ++r)
        sv[kf * 4 + r] = (kbase + kf * 16 + r < cntv) ? pv[kf][r] * QK2L : -1e30f;
    }
    float tmax = sv[0];
    #pragma unroll
    for (int i = 1; i < 16; ++i) tmax = fmaxf(tmax, sv[i]);
    tmax = fmaxf(tmax, __shfl_xor(tmax, 16));
    tmax = fmaxf(tmax, __shfl_xor(tmax, 32));
    float mnew = fmaxf(m, tmax);
    float scale = exp2f(m - mnew);
    float psum = 0.f;
    #pragma unroll
    for (int i = 0; i < 16; ++i) { sv[i] = exp2f(sv[i] - mnew); psum += sv[i]; }
    psum += __shfl_xor(psum, 16);
    psum += __shfl_xor(psum, 32);
    l = l * scale + psum;
    m = mnew;
    #pragma unroll
    for (int df = 0; df < 4; ++df) {
      o[df][0] *= scale; o[df][1] *= scale; o[df][2] *= scale; o[df][3] *= scale;
    }
    // ---- P -> per-wave LDS (bf16, swizzled) ----
    int pbase = wid * 1024 + q * 64;
    #pragma unroll
    for (int kf = 0; kf < 4; ++kf) {
      short4v pk = { f2bf(sv[kf * 4 + 0]), f2bf(sv[kf * 4 + 1]), f2bf(sv[kf * 4 + 2]), f2bf(sv[kf * 4 + 3]) };
      *(short4v*)&Ps[pbase + ((kf * 16 + hi * 4) ^ swz)] = pk;
    }
    // ---- PV ----
    __builtin_amdgcn_s_setprio(1);
    #pragma unroll
    for (int ks = 0; ks < 2; ++ks) {
      bf16x8 pb = *(const bf16x8*)&Ps[pbase + ((ks * 32 + hi * 8) ^ swz)];
      #pragma unroll
      for (int df = 0; df < 4; ++df) {
        bf16x8 vf = *(const bf16x8*)&Vcur[(df * 16 + q) * 64 + ((ks * 32 + hi * 8) ^ swz)];
        o[df] = __builtin_amdgcn_mfma_f32_16x16x32_bf16(vf, pb, o[df], 0, 0, 0);
      }
    }
    __builtin_amdgcn_s_setprio(0);
    asm volatile("s_waitcnt vmcnt(0)" ::: "memory");  // own prefetch landed
    __syncthreads();
  }
  float inv = 1.0f / l;
  short* op = attn_b + ((size_t)(b * S_ + s0 + wid * 16 + q) * KV_ + h * DH_);
  #pragma unroll
  for (int df = 0; df < 4; ++df) {
    short4v ov = { f2bf(o[df][0] * inv), f2bf(o[df][1] * inv), f2bf(o[df][2] * inv), f2bf(o[df][3] * inv) };
    *(short4v*)&op[df * 16 + hi * 4] = ov;
  }
}

// ==================== L6: output projection (stores (B,C,S) directly) ====================
__global__ __launch_bounds__(256) void k_outproj(const short* __restrict__ Wo_b, const short* __restrict__ attn_b,
                                                 const float* __restrict__ bo, float* __restrict__ out) {
  __shared__ short smem[BM * BKG * 2];
  gemm_body<1>(Wo_b, attn_b, bo, out, smem, smem + BM * BKG, blockIdx.x, blockIdx.y, KV_, B_ * S_);
}

extern "C" void kernel_launch(void* const* d_in, const int* in_sizes, int n_in,
                              void* d_out, int out_size, void* d_ws, size_t ws_size,
                              hipStream_t stream) {
  const float* h         = (const float*)d_in[0];
  const float* cond      = (const float*)d_in[1];
  const int*   cond_mask = (const int*)d_in[2];
  const float* Wq = (const float*)d_in[3];
  const float* bq = (const float*)d_in[4];
  const float* Wk = (const float*)d_in[5];
  const float* bk = (const float*)d_in[6];
  const float* Wv = (const float*)d_in[7];
  const float* bv = (const float*)d_in[8];
  const float* Wrk = (const float*)d_in[11];
  const float* brk = (const float*)d_in[12];
  const float* Wo  = (const float*)d_in[13];
  const float* bo  = (const float*)d_in[14];
  float* out = (float*)d_out;

  char* w = (char*)d_ws;
  short* qb      = (short*)(w + 0);          // 8 MB
  short* Kb      = (short*)(w + 8388608);    // 4 MB
  short* Vb      = (short*)(w + 12582912);   // 4 MB (row-major V)
  short* attn_b  = (short*)(w + 16777216);   // 8 MB
  short* hT      = (short*)(w + 25165824);   // 4 MB (dead after L2)
  short* Vtc     = (short*)(w + 25165824);   //   alias hT (written L4)
  short* cond_b  = (short*)(w + 29360128);   // 4 MB
  float* cp_part = (float*)(w + 33554432);   // 4 MB (dead after L2)
  short* Kc      = (short*)(w + 33554432);   //   alias cp_part (written L4)
  float* cp      = (float*)(w + 37748736);   // 1 MB
  int*   idxb    = (int*)  (w + 38797312);   // 16 KB
  int*   cnt     = (int*)  (w + 38813696);   // 64 B
  short* Wq_b    = (short*)(w + 38813760);   // 256 KB
  short* Wk_b    = (short*)(w + 39075904);   // 512 KB
  short* Wv_b    = (short*)(w + 39600192);   // 512 KB
  short* Wo_b    = (short*)(w + 40124480);   // 256 KB

  // L1: converts + h-transpose + selector rel-proj
  k_prep<<<5120, 256, 0, stream>>>(cond, Wq, Wk, Wv, Wo, h, Wrk,
                                   cond_b, Wq_b, Wk_b, Wv_b, Wo_b, hT, cp_part);
  // L2: q/K/V projections (all row-major) + normalize
  k_fused_proj<<<1536, 256, 0, stream>>>(hT, cond_b, Wq_b, Wk_b, Wv_b, bq, bk, bv,
                                         qb, Kb, Vb, cp_part, brk, cp);
  // L3: centrality + top-k + compaction
  k_centrality_select<<<8, 512, 0, stream>>>(cp, cond_mask, idxb, cnt);
  // L4: gather compact K; gather+transpose V
  k_gather<<<576, 256, 0, stream>>>(Kb, Vb, idxb, cnt, Kc, Vtc);
  // L5: attention over compacted keys
  k_attn_mfma<<<dim3(16, 8, 8), 256, 0, stream>>>(qb, Kc, Vtc, cnt, attn_b);
  // L6: output projection -> (B,C,S)
  k_outproj<<<dim3(2, 64), 256, 0, stream>>>(Wo_b, attn_b, bo, out);
}

// Round 8
// 118.482 us; speedup vs baseline: 4.0146x; 1.0514x over previous
//
#include <hip/hip_runtime.h>
#include <math.h>

#define B_ 8
#define C_ 256
#define S_ 1024
#define N_ 512
#define KV_ 512
#define REL_ 64
#define NH_ 8
#define DH_ 64
#define KSEL_ 307

#define BM 128
#define BN 128

typedef __attribute__((ext_vector_type(8))) short bf16x8;
typedef __attribute__((ext_vector_type(4))) short short4v;
typedef __attribute__((ext_vector_type(4))) float f32x4;

__device__ __forceinline__ short f2bf(float f) {
  unsigned int u = __float_as_uint(f);
  u += 0x7fffu + ((u >> 16) & 1u);
  return (short)(u >> 16);
}

// ==================== L1: converts + h-transpose + rel-proj ====================
__global__ __launch_bounds__(256) void k_prep(const float* __restrict__ cond, const float* __restrict__ Wq,
                                              const float* __restrict__ Wk, const float* __restrict__ Wv,
                                              const float* __restrict__ Wo, const float* __restrict__ h,
                                              const float* __restrict__ Wrk,
                                              short* __restrict__ cond_b, short* __restrict__ Wq_b,
                                              short* __restrict__ Wk_b, short* __restrict__ Wv_b,
                                              short* __restrict__ Wo_b, short* __restrict__ hT,
                                              float* __restrict__ cp_part) {
  __shared__ float fs[2176];
  int blk = blockIdx.x, tid = threadIdx.x;
  if (blk < 2816) {
    const float* src; short* dst; int base;
    if (blk < 2048)      { src = cond; dst = cond_b; base = blk; }
    else if (blk < 2176) { src = Wq;   dst = Wq_b;   base = blk - 2048; }
    else if (blk < 2432) { src = Wk;   dst = Wk_b;   base = blk - 2176; }
    else if (blk < 2688) { src = Wv;   dst = Wv_b;   base = blk - 2432; }
    else                 { src = Wo;   dst = Wo_b;   base = blk - 2688; }
    int i = base * 256 + tid;
    float4 v = ((const float4*)src)[i];
    short4v o = { f2bf(v.x), f2bf(v.y), f2bf(v.z), f2bf(v.w) };
    ((short4v*)dst)[i] = o;
  } else if (blk < 4864) {
    int i = blk - 2816;
    int s0 = (i & 31) * 32, c0 = ((i >> 5) & 7) * 32, b = i >> 8;
    int x = tid & 31, y0 = tid >> 5;
    #pragma unroll
    for (int y = y0; y < 32; y += 8)
      fs[y * 33 + x] = h[((size_t)(b * C_ + c0 + y)) * S_ + s0 + x];
    __syncthreads();
    #pragma unroll
    for (int y = y0; y < 32; y += 8)
      hT[((size_t)(b * S_ + s0 + y)) * C_ + c0 + x] = f2bf(fs[x * 33 + y]);
  } else {
    int i = blk - 4864;
    int bm = (i & 63) * 64, kb = i >> 6;
    float* As = fs;
    float* Bs = fs + 1088;
    int tm = (tid >> 4) << 2, tn = (tid & 15) << 2;
    float acc[4][4] = {};
    for (int k0 = kb * 128; k0 < kb * 128 + 128; k0 += 16) {
      #pragma unroll
      for (int ii = 0; ii < 4; ++ii) {
        int idx = tid + ii * 256;
        int r = idx >> 4, k = idx & 15;
        As[r * 17 + k] = cond[(size_t)(bm + r) * KV_ + k0 + k];
        Bs[r * 17 + k] = Wrk[(size_t)r * KV_ + k0 + k];
      }
      __syncthreads();
      #pragma unroll
      for (int k = 0; k < 16; ++k) {
        float a[4], bb[4];
        #pragma unroll
        for (int x = 0; x < 4; ++x) { a[x] = As[(tm + x) * 17 + k]; bb[x] = Bs[(tn + x) * 17 + k]; }
        #pragma unroll
        for (int x = 0; x < 4; ++x)
          #pragma unroll
          for (int y = 0; y < 4; ++y)
            acc[x][y] += a[x] * bb[y];
      }
      __syncthreads();
    }
    #pragma unroll
    for (int x = 0; x < 4; ++x)
      #pragma unroll
      for (int y = 0; y < 4; ++y)
        cp_part[(size_t)kb * 262144 + (size_t)(bm + tm + x) * 64 + tn + y] = acc[x][y];
  }
}

// ==================== MFMA GEMM body: 128x128 tile, BK=32, double-buffered LDS ====================
// LDS layout per operand: [2 bufs][128 rows][32 k] shorts, 64-B rows XOR-swizzled by key (rt>>1)&3.
// MODE 0: bf16 store Cout[row*Nout+col], bias[col]
// MODE 1: f32 store out[((col>>10)*C_ + row)*S_ + (col&1023)], bias[row]   (out-projection)
template<int MODE>
__device__ __forceinline__ void gemm_body(const short* __restrict__ A, const short* __restrict__ W,
                                          const float* __restrict__ bias, void* __restrict__ Cout,
                                          short* As, short* Bs, int bx, int by, int Kd, int Nout) {
  int tid = threadIdx.x;
  int lane = tid & 63, wid = tid >> 6;
  int wr = wid >> 1, wc = wid & 1;
  size_t bm = (size_t)bx * BM, bn = (size_t)by * BN;
  f32x4 acc[4][4] = {};
  int srow = lane >> 2;      // 0..15
  int schunk = lane & 3;     // 16-B chunk within 64-B row
  int steps = Kd >> 5;

  #define STAGE_G(t, buf)                                                                              \
    {                                                                                                  \
      int k0s = (t) * 32;                                                                              \
      _Pragma("unroll")                                                                                \
      for (int i = 0; i < 2; ++i) {                                                                    \
        int rt = wid * 32 + i * 16 + srow;                                                             \
        int sc = (schunk ^ ((rt >> 1) & 3)) * 8;                                                       \
        const short* ga = A + (bm + rt) * Kd + k0s + sc;                                               \
        __builtin_amdgcn_global_load_lds((const __attribute__((address_space(1))) void*)ga,            \
            (__attribute__((address_space(3))) void*)(As + (buf) * 4096 + (wid * 32 + i * 16) * 32),   \
            16, 0, 0);                                                                                 \
        const short* gb = W + (bn + rt) * Kd + k0s + sc;                                               \
        __builtin_amdgcn_global_load_lds((const __attribute__((address_space(1))) void*)gb,            \
            (__attribute__((address_space(3))) void*)(Bs + (buf) * 4096 + (wid * 32 + i * 16) * 32),   \
            16, 0, 0);                                                                                 \
      }                                                                                                \
    }

  STAGE_G(0, 0);
  asm volatile("s_waitcnt vmcnt(0)" ::: "memory");
  __syncthreads();

  for (int t = 0; t < steps; ++t) {
    int cur = t & 1;
    if (t + 1 < steps) STAGE_G(t + 1, cur ^ 1);
    const short* Ac = As + cur * 4096;
    const short* Bc = Bs + cur * 4096;
    bf16x8 a[4], b[4];
    #pragma unroll
    for (int m = 0; m < 4; ++m) {
      int rt = wr * 64 + m * 16 + (lane & 15);
      a[m] = *(const bf16x8*)(Ac + rt * 32 + (((lane >> 4) ^ ((rt >> 1) & 3)) * 8));
    }
    #pragma unroll
    for (int n = 0; n < 4; ++n) {
      int rt = wc * 64 + n * 16 + (lane & 15);
      b[n] = *(const bf16x8*)(Bc + rt * 32 + (((lane >> 4) ^ ((rt >> 1) & 3)) * 8));
    }
    __builtin_amdgcn_s_setprio(1);
    #pragma unroll
    for (int m = 0; m < 4; ++m)
      #pragma unroll
      for (int n = 0; n < 4; ++n)
        acc[m][n] = __builtin_amdgcn_mfma_f32_16x16x32_bf16(a[m], b[n], acc[m][n], 0, 0, 0);
    __builtin_amdgcn_s_setprio(0);
    asm volatile("s_waitcnt vmcnt(0)" ::: "memory");
    __syncthreads();
  }
  #undef STAGE_G

  int c0 = lane & 15, r0q = lane >> 4;
  #pragma unroll
  for (int n = 0; n < 4; ++n) {
    size_t col = bn + wc * 64 + n * 16 + c0;
    #pragma unroll
    for (int m = 0; m < 4; ++m) {
      #pragma unroll
      for (int j = 0; j < 4; ++j) {
        size_t row = bm + wr * 64 + m * 16 + r0q * 4 + j;
        if (MODE == 0) {
          ((short*)Cout)[row * Nout + col] = f2bf(acc[m][n][j] + bias[col]);
        } else {
          ((float*)Cout)[((col >> 10) * C_ + row) * S_ + (col & (S_ - 1))] = acc[m][n][j] + bias[row];
        }
      }
    }
  }
}

// ==================== L2: q/K/V projections + normalize ====================
__global__ __launch_bounds__(256) void k_fused_proj(const short* __restrict__ hT, const short* __restrict__ cond_b,
                                                    const short* __restrict__ Wq_b, const short* __restrict__ Wk_b,
                                                    const short* __restrict__ Wv_b,
                                                    const float* __restrict__ bq, const float* __restrict__ bk,
                                                    const float* __restrict__ bv,
                                                    short* __restrict__ qb, short* __restrict__ Kb,
                                                    short* __restrict__ Vb,
                                                    const float* __restrict__ cp_part, const float* __restrict__ brk,
                                                    float* __restrict__ cp) {
  __shared__ short smem[16384];  // 2 operands x 2 bufs x 128 x 32
  int blk = blockIdx.x;
  if (blk < 256) {
    gemm_body<0>(hT, Wq_b, bq, qb, smem, smem + 8192, blk & 63, blk >> 6, C_, KV_);
  } else if (blk < 384) {
    int i = blk - 256;
    gemm_body<0>(cond_b, Wk_b, bk, Kb, smem, smem + 8192, i & 31, i >> 5, KV_, KV_);
  } else if (blk < 512) {
    int i = blk - 384;
    gemm_body<0>(cond_b, Wv_b, bv, Vb, smem, smem + 8192, i & 31, i >> 5, KV_, KV_);
  } else {
    int i = blk - 512;
    int row = i * 4 + (threadIdx.x >> 6);
    int d = threadIdx.x & 63;
    size_t off = (size_t)row * 64 + d;
    float x = cp_part[off] + cp_part[262144 + off] + cp_part[524288 + off] + cp_part[786432 + off] + brk[d];
    float ss = x * x;
    #pragma unroll
    for (int o = 32; o; o >>= 1) ss += __shfl_xor(ss, o);
    cp[off] = x / fmaxf(sqrtf(ss), 1e-12f);
  }
}

// ==================== L3: centrality + top-k + mask + fallback + index compaction ====================
__global__ __launch_bounds__(512) void k_centrality_select(const float* __restrict__ cp, const int* __restrict__ mask,
                                                           int* __restrict__ idxb, int* __restrict__ cnt) {
  int b = blockIdx.x, tid = threadIdx.x;
  __shared__ float part[8][64];
  __shared__ float vsum[64];
  __shared__ float sc[512];
  __shared__ int wcnt[8];
  int d = tid & 63, g = tid >> 6;
  float sacc = 0.f;
  for (int n = g * 64; n < g * 64 + 64; ++n)
    sacc += cp[((size_t)b * N_ + n) * 64 + d];
  part[g][d] = sacc;
  __syncthreads();
  if (tid < 64) {
    float v = 0.f;
    #pragma unroll
    for (int gg = 0; gg < 8; ++gg) v += part[gg][tid];
    vsum[tid] = v;
  }
  __syncthreads();
  const float* x = cp + ((size_t)b * N_ + tid) * 64;
  float dsum = 0.f, dself = 0.f;
  #pragma unroll
  for (int dd = 0; dd < 64; ++dd) {
    float xv = x[dd];
    dsum += xv * vsum[dd];
    dself += xv * xv;
  }
  sc[tid] = dsum - dself;
  __syncthreads();
  float v = sc[tid];
  int rank = 0;
  for (int j = 0; j < N_; ++j) {
    float u = sc[j];
    rank += (u > v) || (u == v && j < tid);
  }
  int sel = (rank < KSEL_) && (mask[b * N_ + tid] != 0);
  unsigned long long bal = __ballot(sel);
  if ((tid & 63) == 0) wcnt[g] = __popcll(bal);
  __syncthreads();
  int off = 0, total = 0;
  #pragma unroll
  for (int i = 0; i < 8; ++i) { int c = wcnt[i]; total += c; if (i < g) off += c; }
  int pos = off + __popcll(bal & ((1ull << (tid & 63)) - 1ull));
  if (sel) idxb[b * N_ + pos] = tid;
  if (total == 0 && rank == 0) idxb[b * N_] = tid;
  if (tid == 0) cnt[b] = (total == 0) ? 1 : total;
}

// ==================== L4: gather compact K rows; gather+transpose V -> Vtc ====================
__global__ __launch_bounds__(256) void k_gather(const short* __restrict__ Kb, const short* __restrict__ Vb,
                                                const int* __restrict__ idxb, const int* __restrict__ cnt,
                                                short* __restrict__ Kc, short* __restrict__ Vtc) {
  __shared__ short t[64][68];
  int blk = blockIdx.x, tid = threadIdx.x;
  if (blk < 64) {
    int b = blk >> 3, rg = blk & 7;
    int cv = cnt[b], padded = (cv + 63) & ~63;
    #pragma unroll
    for (int it = 0; it < 16; ++it) {
      int e = it * 256 + tid;
      int r = rg * 64 + (e >> 6);
      int ch = e & 63;
      if (r < padded) {
        int4 val = {0, 0, 0, 0};
        if (r < cv) {
          int src = idxb[b * N_ + r];
          val = *(const int4*)(Kb + ((size_t)(b * N_ + src) * KV_) + ch * 8);
        }
        *(int4*)(Kc + ((size_t)(b * N_ + r) * KV_) + ch * 8) = val;
      }
    }
  } else {
    int i2 = blk - 64;
    int b = i2 >> 6, h = (i2 >> 3) & 7, ntb = i2 & 7;
    int cv = cnt[b], padded = (cv + 63) & ~63;
    if (ntb * 64 >= padded) return;
    const int* idxp = idxb + b * N_;
    #pragma unroll
    for (int p = 0; p < 2; ++p) {
      int c = p * 256 + tid;
      int rr = c >> 3, dd8 = (c & 7) * 8;
      int r = ntb * 64 + rr;
      short4v z = {0, 0, 0, 0};
      short4v v0 = z, v1 = z;
      if (r < cv) {
        int gi = idxp[r];
        const short* gp = Vb + (size_t)(b * N_ + gi) * KV_ + h * 64 + dd8;
        v0 = *(const short4v*)gp;
        v1 = *(const short4v*)(gp + 4);
      }
      *(short4v*)&t[rr][dd8] = v0;
      *(short4v*)&t[rr][dd8 + 4] = v1;
    }
    __syncthreads();
    #pragma unroll
    for (int p = 0; p < 2; ++p) {
      int c = p * 256 + tid;
      int dd = c >> 3, rr8 = (c & 7) * 8;
      short4v o0, o1;
      #pragma unroll
      for (int j = 0; j < 4; ++j) o0[j] = t[rr8 + j][dd];
      #pragma unroll
      for (int j = 0; j < 4; ++j) o1[j] = t[rr8 + 4 + j][dd];
      short* op = Vtc + ((size_t)((b * NH_ + h) * DH_) + dd) * N_ + ntb * 64 + rr8;
      *(short4v*)op = o0;
      *(short4v*)(op + 4) = o1;
    }
  }
}

// ==================== staging helpers (layout: LDS[r][c] = G[r][c ^ (r&7)], 128-B rows) ====================
__device__ __forceinline__ void stage_tile64(const short* gRowBase, int gStride, short* ldsBase, int wid, int lane) {
  int sub = lane >> 3;
  int colE = ((lane & 7) ^ sub) * 8;
  #pragma unroll
  for (int i = 0; i < 2; ++i) {
    int r = wid * 16 + i * 8 + sub;
    const short* gp = gRowBase + (size_t)r * gStride + colE;
    __builtin_amdgcn_global_load_lds((const __attribute__((address_space(1))) void*)gp,
                                     (__attribute__((address_space(3))) void*)(ldsBase + wid * 1024 + i * 512),
                                     16, 0, 0);
  }
}
// 8-wave variant for a 64-row tile (1 instr/wave): same LDS layout.
__device__ __forceinline__ void stage_tile64_w8(const short* gRowBase, int gStride, short* ldsBase, int wid, int lane) {
  int sub = lane >> 3;
  int colE = ((lane & 7) ^ sub) * 8;
  int r = wid * 8 + sub;
  const short* gp = gRowBase + (size_t)r * gStride + colE;
  __builtin_amdgcn_global_load_lds((const __attribute__((address_space(1))) void*)gp,
                                   (__attribute__((address_space(3))) void*)(ldsBase + wid * 512),
                                   16, 0, 0);
}

// ==================== L5: MFMA flash attention, 128 q-rows/block, 8 waves, XCD-grouped grid ====================
#define QK2L 0.18033688f  // 0.125 * log2(e)
__global__ __launch_bounds__(512) void k_attn_mfma(const short* __restrict__ qb, const short* __restrict__ Kc,
                                                   const short* __restrict__ Vtc, const int* __restrict__ cnt,
                                                   short* __restrict__ attn_b) {
  __shared__ short Qs[8192];
  __shared__ short Ks[2][4096];
  __shared__ short Vs[2][4096];
  __shared__ short Ps[8192];
  // XCD-grouping remap: 512 blocks = 8 XCDs x (8 bh-groups x 8 q-tiles)
  int g = blockIdx.x;
  int xcd = g & 7, li = g >> 3;
  int bh = xcd * 8 + (li >> 3);
  int qt = li & 7;
  int b = bh >> 3, h = bh & 7;
  int tid = threadIdx.x, lane = tid & 63, wid = tid >> 6;
  int hi = lane >> 4, q = lane & 15;
  int s0 = qt * 128;
  int cntv = cnt[b];
  int nt = (cntv + 63) >> 6;
  const short* Qg = qb + ((size_t)(b * S_ + s0) * KV_ + h * DH_);
  const short* Kg = Kc + ((size_t)(b * N_) * KV_ + h * DH_);
  const short* Vg = Vtc + ((size_t)((b * NH_ + h) * DH_) * N_);

  stage_tile64(Qg, KV_, Qs, wid, lane);          // 8 waves x 16 rows = 128 rows
  stage_tile64_w8(Kg, KV_, Ks[0], wid, lane);
  stage_tile64_w8(Vg, N_, Vs[0], wid, lane);
  asm volatile("s_waitcnt vmcnt(0)" ::: "memory");
  __syncthreads();

  int swz = (lane & 7) << 3;
  bf16x8 qf0 = *(const bf16x8*)&Qs[(wid * 16 + q) * 64 + ((hi * 8) ^ swz)];
  bf16x8 qf1 = *(const bf16x8*)&Qs[(wid * 16 + q) * 64 + ((32 + hi * 8) ^ swz)];

  float m = -1e30f, l = 0.f;
  f32x4 o[4] = {};

  for (int t = 0; t < nt; ++t) {
    int cur = t & 1;
    const short* Kcur = Ks[cur];
    const short* Vcur = Vs[cur];
    if (t + 1 < nt) {
      stage_tile64_w8(Kg + (size_t)(t + 1) * 64 * KV_, KV_, Ks[cur ^ 1], wid, lane);
      stage_tile64_w8(Vg + (t + 1) * 64, N_, Vs[cur ^ 1], wid, lane);
    }
    // ---- QK^T ----
    f32x4 pv[4];
    __builtin_amdgcn_s_setprio(1);
    #pragma unroll
    for (int kf = 0; kf < 4; ++kf) {
      bf16x8 k0 = *(const bf16x8*)&Kcur[(kf * 16 + q) * 64 + ((hi * 8) ^ swz)];
      bf16x8 k1 = *(const bf16x8*)&Kcur[(kf * 16 + q) * 64 + ((32 + hi * 8) ^ swz)];
      f32x4 z = {0.f, 0.f, 0.f, 0.f};
      pv[kf] = __builtin_amdgcn_mfma_f32_16x16x32_bf16(k0, qf0, z, 0, 0, 0);
      pv[kf] = __builtin_amdgcn_mfma_f32_16x16x32_bf16(k1, qf1, pv[kf], 0, 0, 0);
    }
    __builtin_amdgcn_s_setprio(0);
    // ---- mask + online softmax (log2 domain) ----
    float sv[16];
    int kbase = t * 64 + hi * 4;
    #pragma unroll
    for (int kf = 0; kf < 4; ++kf) {
      #pragma unroll
      for (int r = 0; r < 4; ++r)
        sv[kf * 4 + r] = (kbase + kf * 16 + r < cntv) ? pv[kf][r] * QK2L : -1e30f;
    }
    float tmax = sv[0];
    #pragma unroll
    for (int i = 1; i < 16; ++i) tmax = fmaxf(tmax, sv[i]);
    tmax = fmaxf(tmax, __shfl_xor(tmax, 16));
    tmax = fmaxf(tmax, __shfl_xor(tmax, 32));
    float mnew = fmaxf(m, tmax);
    float scale = exp2f(m - mnew);
    float psum = 0.f;
    #pragma unroll
    for (int i = 0; i < 16; ++i) { sv[i] = exp2f(sv[i] - mnew); psum += sv[i]; }
    psum += __shfl_xor(psum, 16);
    psum += __shfl_xor(psum, 32);
    l = l * scale + psum;
    m = mnew;
    #pragma unroll
    for (int df = 0; df < 4; ++df) {
      o[df][0] *= scale; o[df][1] *= scale; o[df][2] *= scale; o[df][3] *= scale;
    }
    // ---- P -> per-wave LDS (bf16, swizzled) ----
    int pbase = wid * 1024 + q * 64;
    #pragma unroll
    for (int kf = 0; kf < 4; ++kf) {
      short4v pk = { f2bf(sv[kf * 4 + 0]), f2bf(sv[kf * 4 + 1]), f2bf(sv[kf * 4 + 2]), f2bf(sv[kf * 4 + 3]) };
      *(short4v*)&Ps[pbase + ((kf * 16 + hi * 4) ^ swz)] = pk;
    }
    // ---- PV ----
    __builtin_amdgcn_s_setprio(1);
    #pragma unroll
    for (int ks = 0; ks < 2; ++ks) {
      bf16x8 pb = *(const bf16x8*)&Ps[pbase + ((ks * 32 + hi * 8) ^ swz)];
      #pragma unroll
      for (int df = 0; df < 4; ++df) {
        bf16x8 vf = *(const bf16x8*)&Vcur[(df * 16 + q) * 64 + ((ks * 32 + hi * 8) ^ swz)];
        o[df] = __builtin_amdgcn_mfma_f32_16x16x32_bf16(vf, pb, o[df], 0, 0, 0);
      }
    }
    __builtin_amdgcn_s_setprio(0);
    asm volatile("s_waitcnt vmcnt(0)" ::: "memory");
    __syncthreads();
  }
  float inv = 1.0f / l;
  short* op = attn_b + ((size_t)(b * S_ + s0 + wid * 16 + q) * KV_ + h * DH_);
  #pragma unroll
  for (int df = 0; df < 4; ++df) {
    short4v ov = { f2bf(o[df][0] * inv), f2bf(o[df][1] * inv), f2bf(o[df][2] * inv), f2bf(o[df][3] * inv) };
    *(short4v*)&op[df * 16 + hi * 4] = ov;
  }
}

// ==================== L6: output projection (stores (B,C,S) directly) ====================
__global__ __launch_bounds__(256) void k_outproj(const short* __restrict__ Wo_b, const short* __restrict__ attn_b,
                                                 const float* __restrict__ bo, float* __restrict__ out) {
  __shared__ short smem[16384];
  gemm_body<1>(Wo_b, attn_b, bo, out, smem, smem + 8192, blockIdx.x, blockIdx.y, KV_, B_ * S_);
}

extern "C" void kernel_launch(void* const* d_in, const int* in_sizes, int n_in,
                              void* d_out, int out_size, void* d_ws, size_t ws_size,
                              hipStream_t stream) {
  const float* h         = (const float*)d_in[0];
  const float* cond      = (const float*)d_in[1];
  const int*   cond_mask = (const int*)d_in[2];
  const float* Wq = (const float*)d_in[3];
  const float* bq = (const float*)d_in[4];
  const float* Wk = (const float*)d_in[5];
  const float* bk = (const float*)d_in[6];
  const float* Wv = (const float*)d_in[7];
  const float* bv = (const float*)d_in[8];
  const float* Wrk = (const float*)d_in[11];
  const float* brk = (const float*)d_in[12];
  const float* Wo  = (const float*)d_in[13];
  const float* bo  = (const float*)d_in[14];
  float* out = (float*)d_out;

  char* w = (char*)d_ws;
  short* qb      = (short*)(w + 0);          // 8 MB
  short* Kb      = (short*)(w + 8388608);    // 4 MB
  short* Vb      = (short*)(w + 12582912);   // 4 MB (row-major V)
  short* attn_b  = (short*)(w + 16777216);   // 8 MB
  short* hT      = (short*)(w + 25165824);   // 4 MB (dead after L2)
  short* Vtc     = (short*)(w + 25165824);   //   alias hT (written L4)
  short* cond_b  = (short*)(w + 29360128);   // 4 MB
  float* cp_part = (float*)(w + 33554432);   // 4 MB (dead after L2)
  short* Kc      = (short*)(w + 33554432);   //   alias cp_part (written L4)
  float* cp      = (float*)(w + 37748736);   // 1 MB
  int*   idxb    = (int*)  (w + 38797312);   // 16 KB
  int*   cnt     = (int*)  (w + 38813696);   // 64 B
  short* Wq_b    = (short*)(w + 38813760);   // 256 KB
  short* Wk_b    = (short*)(w + 39075904);   // 512 KB
  short* Wv_b    = (short*)(w + 39600192);   // 512 KB
  short* Wo_b    = (short*)(w + 40124480);   // 256 KB

  // L1: converts + h-transpose + selector rel-proj
  k_prep<<<5120, 256, 0, stream>>>(cond, Wq, Wk, Wv, Wo, h, Wrk,
                                   cond_b, Wq_b, Wk_b, Wv_b, Wo_b, hT, cp_part);
  // L2: q/K/V projections (dbuf BK=32 GEMMs) + normalize
  k_fused_proj<<<1536, 256, 0, stream>>>(hT, cond_b, Wq_b, Wk_b, Wv_b, bq, bk, bv,
                                         qb, Kb, Vb, cp_part, brk, cp);
  // L3: centrality + top-k + compaction
  k_centrality_select<<<8, 512, 0, stream>>>(cp, cond_mask, idxb, cnt);
  // L4: gather compact K; gather+transpose V
  k_gather<<<576, 256, 0, stream>>>(Kb, Vb, idxb, cnt, Kc, Vtc);
  // L5: attention over compacted keys (128 q/block, XCD-grouped)
  k_attn_mfma<<<512, 512, 0, stream>>>(qb, Kc, Vtc, cnt, attn_b);
  // L6: output projection -> (B,C,S)
  k_outproj<<<dim3(2, 64), 256, 0, stream>>>(Wo_b, attn_b, bo, out);
}